// Round 1
// baseline (1389.910 us; speedup 1.0000x reference)
//
#include <hip/hip_runtime.h>
#include <cstddef>

#define EDIM 1024
#define NHEAD 16
#define HDIM 64
#define NB 4
#define LQ 512
#define SK 1024
#define BHD 64  // NB*NHEAD

// ---------------- GEMM: Y = act((X @ W + bias) * scale) ----------------
// X: [M, 1024] row-major, W: [1024, 1024] row-major (in,out), bias: [1024]
// OUTMODE 0: Y plain [M, 1024].
// OUTMODE 1: head-split: token t = l*NB + b, col e = h*64 + d ->
//            Y[((b*NHEAD + h)*seqlen + l)*64 + d]
// ACT 0: none, 1: sigmoid
template<int OUTMODE, int ACT, bool SCALE>
__global__ __launch_bounds__(256)
void gemm_e(const float* __restrict__ X, const float* __restrict__ W,
            const float* __restrict__ bias, float* __restrict__ Y,
            int seqlen, float scale)
{
    __shared__ float As[16][68];  // As[k][m], +4 pad keeps float4 alignment
    __shared__ float Bs[16][68];  // Bs[k][n]
    const int tid = threadIdx.x;
    const int tx = tid & 15, ty = tid >> 4;
    const int row0 = blockIdx.y * 64;
    const int col0 = blockIdx.x * 64;
    const int ar = tid >> 2, ak = (tid & 3) * 4;   // A tile: 64 rows x 16 k
    const int bk = tid >> 4, bc = (tid & 15) * 4;  // B tile: 16 k x 64 cols
    float acc[4][4] = {};
    for (int k0 = 0; k0 < EDIM; k0 += 16) {
        float4 av = *reinterpret_cast<const float4*>(X + (size_t)(row0 + ar) * EDIM + k0 + ak);
        float4 bv = *reinterpret_cast<const float4*>(W + (size_t)(k0 + bk) * EDIM + col0 + bc);
        __syncthreads();
        As[ak + 0][ar] = av.x; As[ak + 1][ar] = av.y;
        As[ak + 2][ar] = av.z; As[ak + 3][ar] = av.w;
        *reinterpret_cast<float4*>(&Bs[bk][bc]) = bv;
        __syncthreads();
#pragma unroll
        for (int k = 0; k < 16; ++k) {
            float a[4], b[4];
#pragma unroll
            for (int i = 0; i < 4; ++i) a[i] = As[k][ty + 16 * i];
#pragma unroll
            for (int j = 0; j < 4; ++j) b[j] = Bs[k][tx + 16 * j];
#pragma unroll
            for (int i = 0; i < 4; ++i)
#pragma unroll
                for (int j = 0; j < 4; ++j)
                    acc[i][j] = fmaf(a[i], b[j], acc[i][j]);
        }
    }
#pragma unroll
    for (int i = 0; i < 4; ++i) {
        const int r = row0 + ty + 16 * i;
#pragma unroll
        for (int j = 0; j < 4; ++j) {
            const int c = col0 + tx + 16 * j;
            float v = acc[i][j] + bias[c];
            if (SCALE) v *= scale;
            if (ACT == 1) v = 1.0f / (1.0f + __expf(-v));
            if (OUTMODE == 0) {
                Y[(size_t)r * EDIM + c] = v;
            } else {
                const int l = r >> 2, b = r & 3;
                const int h = c >> 6, d = c & 63;
                Y[(((size_t)(b * NHEAD + h)) * seqlen + l) * HDIM + d] = v;
            }
        }
    }
}

// ---------------- per-row norms ----------------
__global__ __launch_bounds__(256)
void norms_q_kernel(const float* __restrict__ Q, float* __restrict__ ll)
{
    const int wave = threadIdx.x >> 6, lane = threadIdx.x & 63;
    const int row = blockIdx.x * 4 + wave;  // BHD*LQ rows
    float x = Q[(size_t)row * HDIM + lane];
    float s = x * x;
#pragma unroll
    for (int o = 1; o < 64; o <<= 1) s += __shfl_xor(s, o);
    if (lane == 0) ll[row] = s;
}

__global__ __launch_bounds__(256)
void norms_k_kernel(const float* __restrict__ K1, const float* __restrict__ K2,
                    float* __restrict__ vv, float* __restrict__ aa, float* __restrict__ va)
{
    const int wave = threadIdx.x >> 6, lane = threadIdx.x & 63;
    const int row = blockIdx.x * 4 + wave;  // BHD*SK rows
    float x1 = K1[(size_t)row * HDIM + lane];
    float x2 = K2[(size_t)row * HDIM + lane];
    float s1 = x1 * x1, s2 = x2 * x2, s3 = x1 * x2;
#pragma unroll
    for (int o = 1; o < 64; o <<= 1) {
        s1 += __shfl_xor(s1, o);
        s2 += __shfl_xor(s2, o);
        s3 += __shfl_xor(s3, o);
    }
    if (lane == 0) { vv[row] = s1; aa[row] = s2; va[row] = s3; }
}

// ---------------- scores: logits = lv + la - 1.5*sqrt(max(det, eps)) -------
__global__ __launch_bounds__(256)
void scores_kernel(const float* __restrict__ Q, const float* __restrict__ K1,
                   const float* __restrict__ K2, const float* __restrict__ ll,
                   const float* __restrict__ vv, const float* __restrict__ aa,
                   const float* __restrict__ va, float* __restrict__ logits)
{
    __shared__ float Qs[64][68], K1s[64][68], K2s[64][68];  // [d][row]
    const int tid = threadIdx.x;
    const int tx = tid & 15, ty = tid >> 4;
    const int bh = blockIdx.z;
    const int l0 = blockIdx.y * 64;
    const int s0 = blockIdx.x * 64;
    const float* Qb  = Q  + (size_t)bh * LQ * HDIM;
    const float* K1b = K1 + (size_t)bh * SK * HDIM;
    const float* K2b = K2 + (size_t)bh * SK * HDIM;
    const int r = tid >> 2, dc = (tid & 3) * 16;
#pragma unroll
    for (int u = 0; u < 4; ++u) {
        const int d = dc + u * 4;
        float4 qv  = *reinterpret_cast<const float4*>(Qb  + (size_t)(l0 + r) * HDIM + d);
        float4 k1v = *reinterpret_cast<const float4*>(K1b + (size_t)(s0 + r) * HDIM + d);
        float4 k2v = *reinterpret_cast<const float4*>(K2b + (size_t)(s0 + r) * HDIM + d);
        Qs[d + 0][r] = qv.x;  Qs[d + 1][r] = qv.y;  Qs[d + 2][r] = qv.z;  Qs[d + 3][r] = qv.w;
        K1s[d + 0][r] = k1v.x; K1s[d + 1][r] = k1v.y; K1s[d + 2][r] = k1v.z; K1s[d + 3][r] = k1v.w;
        K2s[d + 0][r] = k2v.x; K2s[d + 1][r] = k2v.y; K2s[d + 2][r] = k2v.z; K2s[d + 3][r] = k2v.w;
    }
    __syncthreads();
    float lv[4][4] = {}, la[4][4] = {};
#pragma unroll 16
    for (int k = 0; k < 64; ++k) {
        float a[4], b1[4], b2[4];
#pragma unroll
        for (int i = 0; i < 4; ++i) a[i] = Qs[k][ty + 16 * i];
#pragma unroll
        for (int j = 0; j < 4; ++j) { b1[j] = K1s[k][tx + 16 * j]; b2[j] = K2s[k][tx + 16 * j]; }
#pragma unroll
        for (int i = 0; i < 4; ++i)
#pragma unroll
            for (int j = 0; j < 4; ++j) {
                lv[i][j] = fmaf(a[i], b1[j], lv[i][j]);
                la[i][j] = fmaf(a[i], b2[j], la[i][j]);
            }
    }
#pragma unroll
    for (int i = 0; i < 4; ++i) {
        const int rl = l0 + ty + 16 * i;
        const float LL = ll[(size_t)bh * LQ + rl];
#pragma unroll
        for (int j = 0; j < 4; ++j) {
            const int cs = s0 + tx + 16 * j;
            const float VV = vv[(size_t)bh * SK + cs];
            const float AA = aa[(size_t)bh * SK + cs];
            const float VA = va[(size_t)bh * SK + cs];
            const float LV = lv[i][j], LA = la[i][j];
            float det = LL * (VV * AA - VA * VA) - LV * (LV * AA - LA * VA) + LA * (LV * VA - LA * VV);
            det = fmaxf(det, 1e-8f);
            logits[((size_t)bh * LQ + rl) * SK + cs] = LV + LA - 1.5f * sqrtf(det);
        }
    }
}

// ---------------- row softmax in place ----------------
__global__ __launch_bounds__(256)
void softmax_kernel(float* __restrict__ attn)
{
    float4* p = reinterpret_cast<float4*>(attn + (size_t)blockIdx.x * SK);
    float4 v = p[threadIdx.x];
    const int wave = threadIdx.x >> 6, lane = threadIdx.x & 63;
    __shared__ float redm[4], reds[4];
    float m = fmaxf(fmaxf(v.x, v.y), fmaxf(v.z, v.w));
#pragma unroll
    for (int o = 1; o < 64; o <<= 1) m = fmaxf(m, __shfl_xor(m, o));
    if (lane == 0) redm[wave] = m;
    __syncthreads();
    m = fmaxf(fmaxf(redm[0], redm[1]), fmaxf(redm[2], redm[3]));
    v.x = __expf(v.x - m); v.y = __expf(v.y - m);
    v.z = __expf(v.z - m); v.w = __expf(v.w - m);
    float s = v.x + v.y + v.z + v.w;
#pragma unroll
    for (int o = 1; o < 64; o <<= 1) s += __shfl_xor(s, o);
    if (lane == 0) reds[wave] = s;
    __syncthreads();
    s = reds[0] + reds[1] + reds[2] + reds[3];
    const float inv = 1.0f / s;
    v.x *= inv; v.y *= inv; v.z *= inv; v.w *= inv;
    p[threadIdx.x] = v;
}

// ---------------- mean over heads -> avg_weights [B, L, S] ----------------
__global__ __launch_bounds__(256)
void head_avg_kernel(const float* __restrict__ attn, float* __restrict__ out)
{
    const size_t idx = (size_t)blockIdx.x * 256 + threadIdx.x;  // B*L*S
    const int s = idx & (SK - 1);
    const size_t bl = idx >> 10;
    const int l = bl & (LQ - 1);
    const int b = (int)(bl >> 9);
    float acc = 0.f;
#pragma unroll
    for (int h = 0; h < NHEAD; ++h)
        acc += attn[(((size_t)(b * NHEAD + h)) * LQ + l) * SK + s];
    out[idx] = acc * (1.0f / NHEAD);
}

// ---------------- PV (v1 & v2 fused) + gating -> tmp [L*B, E] -------------
__global__ __launch_bounds__(256)
void pv_gate_kernel(const float* __restrict__ attn, const float* __restrict__ V1,
                    const float* __restrict__ V2, const float* __restrict__ G1,
                    const float* __restrict__ G2, float* __restrict__ tmp)
{
    __shared__ float At[32][68], V1s[32][68], V2s[32][68];  // At[s][l], Vs[s][d]
    const int tid = threadIdx.x;
    const int tx = tid & 15, ty = tid >> 4;
    const int bh = blockIdx.y;
    const int l0 = blockIdx.x * 64;
    const float* Ab  = attn + (size_t)bh * LQ * SK;
    const float* V1b = V1 + (size_t)bh * SK * HDIM;
    const float* V2b = V2 + (size_t)bh * SK * HDIM;
    const int al = tid >> 2, as0 = (tid & 3) * 8;
    const int vs = tid >> 3, vd = (tid & 7) * 8;
    float acc1[4][4] = {}, acc2[4][4] = {};
    for (int s0 = 0; s0 < SK; s0 += 32) {
        float4 a0  = *reinterpret_cast<const float4*>(Ab + (size_t)(l0 + al) * SK + s0 + as0);
        float4 a1  = *reinterpret_cast<const float4*>(Ab + (size_t)(l0 + al) * SK + s0 + as0 + 4);
        float4 w10 = *reinterpret_cast<const float4*>(V1b + (size_t)(s0 + vs) * HDIM + vd);
        float4 w11 = *reinterpret_cast<const float4*>(V1b + (size_t)(s0 + vs) * HDIM + vd + 4);
        float4 w20 = *reinterpret_cast<const float4*>(V2b + (size_t)(s0 + vs) * HDIM + vd);
        float4 w21 = *reinterpret_cast<const float4*>(V2b + (size_t)(s0 + vs) * HDIM + vd + 4);
        __syncthreads();
        At[as0 + 0][al] = a0.x; At[as0 + 1][al] = a0.y; At[as0 + 2][al] = a0.z; At[as0 + 3][al] = a0.w;
        At[as0 + 4][al] = a1.x; At[as0 + 5][al] = a1.y; At[as0 + 6][al] = a1.z; At[as0 + 7][al] = a1.w;
        *reinterpret_cast<float4*>(&V1s[vs][vd]) = w10;
        *reinterpret_cast<float4*>(&V1s[vs][vd + 4]) = w11;
        *reinterpret_cast<float4*>(&V2s[vs][vd]) = w20;
        *reinterpret_cast<float4*>(&V2s[vs][vd + 4]) = w21;
        __syncthreads();
#pragma unroll
        for (int k = 0; k < 32; ++k) {
            float a[4], b1[4], b2[4];
#pragma unroll
            for (int i = 0; i < 4; ++i) a[i] = At[k][ty + 16 * i];
#pragma unroll
            for (int j = 0; j < 4; ++j) { b1[j] = V1s[k][tx + 16 * j]; b2[j] = V2s[k][tx + 16 * j]; }
#pragma unroll
            for (int i = 0; i < 4; ++i)
#pragma unroll
                for (int j = 0; j < 4; ++j) {
                    acc1[i][j] = fmaf(a[i], b1[j], acc1[i][j]);
                    acc2[i][j] = fmaf(a[i], b2[j], acc2[i][j]);
                }
        }
    }
    const int b = bh >> 4, h = bh & 15;
#pragma unroll
    for (int i = 0; i < 4; ++i) {
        const int rl = l0 + ty + 16 * i;
#pragma unroll
        for (int j = 0; j < 4; ++j) {
            const int d = tx + 16 * j;
            const size_t addr = ((size_t)rl * NB + b) * EDIM + h * HDIM + d;
            tmp[addr] = 0.5f * (acc1[i][j] * G1[addr] + acc2[i][j] * G2[addr]);
        }
    }
}

extern "C" void kernel_launch(void* const* d_in, const int* in_sizes, int n_in,
                              void* d_out, int out_size, void* d_ws, size_t ws_size,
                              hipStream_t stream)
{
    const float* query = (const float*)d_in[0];
    const float* mod1  = (const float*)d_in[1];
    const float* mod2  = (const float*)d_in[2];
    const float* q_w  = (const float*)d_in[3];  const float* q_b  = (const float*)d_in[4];
    const float* k1_w = (const float*)d_in[5];  const float* k1_b = (const float*)d_in[6];
    const float* k2_w = (const float*)d_in[7];  const float* k2_b = (const float*)d_in[8];
    const float* v1_w = (const float*)d_in[9];  const float* v1_b = (const float*)d_in[10];
    const float* v2_w = (const float*)d_in[11]; const float* v2_b = (const float*)d_in[12];
    const float* g1_w = (const float*)d_in[13]; const float* g1_b = (const float*)d_in[14];
    const float* g2_w = (const float*)d_in[15]; const float* g2_b = (const float*)d_in[16];
    const float* o_w  = (const float*)d_in[17]; const float* o_b  = (const float*)d_in[18];
    float* out = (float*)d_out;

    float* ws = (float*)d_ws;
    float* Q  = ws;                         // 2,097,152  (reused later as tmp)
    float* K1 = Q  + (size_t)2097152;       // 4,194,304
    float* K2 = K1 + (size_t)4194304;
    float* V1 = K2 + (size_t)4194304;
    float* V2 = V1 + (size_t)4194304;
    float* G1 = V2 + (size_t)4194304;       // 2,097,152
    float* G2 = G1 + (size_t)2097152;
    float* ll = G2 + (size_t)2097152;       // 32,768
    float* vv = ll + 32768;                 // 65,536
    float* aa = vv + 65536;
    float* va = aa + 65536;
    float* logits = va + 65536;             // 33,554,432 (attn in place)
    float* tmp = Q;                         // Q dead after scores

    const float scaling = 0.125f;  // DH^-0.5

    // projections
    gemm_e<1, 0, true ><<<dim3(16, 32), 256, 0, stream>>>(query, q_w,  q_b,  Q,  LQ, scaling);
    gemm_e<1, 0, false><<<dim3(16, 64), 256, 0, stream>>>(mod1,  k1_w, k1_b, K1, SK, 1.0f);
    gemm_e<1, 0, false><<<dim3(16, 64), 256, 0, stream>>>(mod2,  k2_w, k2_b, K2, SK, 1.0f);
    gemm_e<1, 0, false><<<dim3(16, 64), 256, 0, stream>>>(mod1,  v1_w, v1_b, V1, SK, 1.0f);
    gemm_e<1, 0, false><<<dim3(16, 64), 256, 0, stream>>>(mod2,  v2_w, v2_b, V2, SK, 1.0f);
    gemm_e<0, 1, false><<<dim3(16, 32), 256, 0, stream>>>(query, g1_w, g1_b, G1, 0,  1.0f);
    gemm_e<0, 1, false><<<dim3(16, 32), 256, 0, stream>>>(query, g2_w, g2_b, G2, 0,  1.0f);

    // norms for the gram determinant
    norms_q_kernel<<<8192,  256, 0, stream>>>(Q, ll);
    norms_k_kernel<<<16384, 256, 0, stream>>>(K1, K2, vv, aa, va);

    // logits, softmax, head-average
    scores_kernel<<<dim3(16, 8, BHD), 256, 0, stream>>>(Q, K1, K2, ll, vv, aa, va, logits);
    softmax_kernel<<<BHD * LQ, 256, 0, stream>>>(logits);
    head_avg_kernel<<<8192, 256, 0, stream>>>(logits, out + (size_t)LQ * NB * EDIM);

    // PV + gating, then output projection
    pv_gate_kernel<<<dim3(8, BHD), 256, 0, stream>>>(logits, V1, V2, G1, G2, tmp);
    gemm_e<0, 0, false><<<dim3(16, 32), 256, 0, stream>>>(tmp, o_w, o_b, out, 0, 1.0f);
}

// Round 2
// 513.956 us; speedup vs baseline: 2.7043x; 2.7043x over previous
//
#include <hip/hip_runtime.h>
#include <cstddef>
#include <cstdint>

typedef unsigned short ushort_t;
typedef unsigned int uint_t;
typedef __attribute__((ext_vector_type(8))) short short8;
typedef __attribute__((ext_vector_type(4))) float f32x4;

#define EDIM 1024
#define NHEAD 16
#define HDIM 64
#define NB 4
#define LQ 512
#define SK 1024
#define BHD 64

// ---- bf16 helpers (manual RNE, bit-exact and header-version-proof) ----
__device__ __forceinline__ ushort_t f2b(float f) {
    uint_t u = __float_as_uint(f);
    return (ushort_t)((u + 0x7fffu + ((u >> 16) & 1u)) >> 16);
}
__device__ __forceinline__ float b2f(ushort_t b) {
    return __uint_as_float(((uint_t)b) << 16);
}

// ---- async global->LDS, 16B per lane, wave-uniform LDS base ----
__device__ __forceinline__ void gload_lds16(const void* g, void* l) {
    __builtin_amdgcn_global_load_lds((const __attribute__((address_space(1))) void*)g,
                                     (__attribute__((address_space(3))) void*)l, 16, 0, 0);
}

// =================== bf16 MFMA GEMM, 128x128 tile, K=1024 ===================
// A [M][1024] row-major bf16 ; B^T [1024 n][1024 k] row-major bf16
// OUTMODE 0: fp32 [t][1024] (+bias)            (o-proj)
// OUTMODE 1: fp32 head-split [bh][s][64]       (k/v)
// OUTMODE 2: bf16 head-split, (acc+bias)*scale (q)
// OUTMODE 3: fp32 [t][1024], sigmoid           (gates)
// SPLIT: 3-pass hi/lo split precision (AhBh + AhBl + AlBh)
template<int OUTMODE, int SPLIT>
__global__ __launch_bounds__(256, 2)
void gemm_mfma(const ushort_t* __restrict__ Ah, const ushort_t* __restrict__ Al,
               const ushort_t* __restrict__ Bh, const ushort_t* __restrict__ Bl,
               const float* __restrict__ bias, void* __restrict__ Yv,
               int seqlen, float scale)
{
    __shared__ ushort_t As[128 * 64];
    __shared__ ushort_t Bs[128 * 64];
    const int tid = threadIdx.x;
    const int wave = tid >> 6, lane = tid & 63;
    const int ln = lane & 15, lq = lane >> 4;
    const int row0 = blockIdx.y * 128, col0 = blockIdx.x * 128;
    const int wm = wave & 1, wn = wave >> 1;
    const int cswz = (lane & 7) ^ ((lane >> 3) & 7);  // swizzled chunk to fetch
    const int mrl = lane >> 3;                        // row-within-8 for staging

    f32x4 zero = {0.f, 0.f, 0.f, 0.f};
    f32x4 acc[4][4];
#pragma unroll
    for (int i = 0; i < 4; ++i)
#pragma unroll
        for (int j = 0; j < 4; ++j) acc[i][j] = zero;

    const int NPASS = SPLIT ? 3 : 1;
    for (int pp = 0; pp < NPASS; ++pp) {
        const ushort_t* Ab = (pp == 2) ? Al : Ah;
        const ushort_t* Bb = (pp == 1) ? Bl : Bh;
        for (int kk = 0; kk < 1024; kk += 64) {
            __syncthreads();
#pragma unroll
            for (int j = 0; j < 4; ++j) {
                const int mr = (wave * 4 + j) * 8 + mrl;
                gload_lds16(Ab + (size_t)(row0 + mr) * 1024 + kk + cswz * 8,
                            (void*)(As + (wave * 4 + j) * 512));
                gload_lds16(Bb + (size_t)(col0 + mr) * 1024 + kk + cswz * 8,
                            (void*)(Bs + (wave * 4 + j) * 512));
            }
            __syncthreads();
#pragma unroll
            for (int sub = 0; sub < 2; ++sub) {
                short8 af[4], bfv[4];
#pragma unroll
                for (int i = 0; i < 4; ++i) {
                    const int ml = wm * 64 + i * 16 + ln;
                    af[i] = *(const short8*)(As + ml * 64 + (((sub * 4 + lq) ^ (ml & 7)) * 8));
                    const int nl = wn * 64 + i * 16 + ln;
                    bfv[i] = *(const short8*)(Bs + nl * 64 + (((sub * 4 + lq) ^ (nl & 7)) * 8));
                }
#pragma unroll
                for (int i = 0; i < 4; ++i)
#pragma unroll
                    for (int j = 0; j < 4; ++j)
                        acc[i][j] = __builtin_amdgcn_mfma_f32_16x16x32_bf16(af[i], bfv[j], acc[i][j], 0, 0, 0);
            }
        }
    }

#pragma unroll
    for (int i = 0; i < 4; ++i) {
#pragma unroll
        for (int r = 0; r < 4; ++r) {
            const int row = row0 + wm * 64 + i * 16 + lq * 4 + r;
#pragma unroll
            for (int j = 0; j < 4; ++j) {
                const int col = col0 + wn * 64 + j * 16 + ln;
                float v = acc[i][j][r] + bias[col];
                if (OUTMODE == 0) {
                    ((float*)Yv)[(size_t)row * 1024 + col] = v;
                } else if (OUTMODE == 1) {
                    const int s = row >> 2, b = row & 3, h = col >> 6, d = col & 63;
                    ((float*)Yv)[(((size_t)(b * 16 + h)) * seqlen + s) * 64 + d] = v;
                } else if (OUTMODE == 2) {
                    v *= scale;
                    const int s = row >> 2, b = row & 3, h = col >> 6, d = col & 63;
                    ((ushort_t*)Yv)[(((size_t)(b * 16 + h)) * seqlen + s) * 64 + d] = f2b(v);
                } else {
                    v = 1.0f / (1.0f + __expf(-v));
                    ((float*)Yv)[(size_t)row * 1024 + col] = v;
                }
            }
        }
    }
}

// =================== input casts ===================
__global__ __launch_bounds__(256)
void cast_q_kernel(const float* __restrict__ x, ushort_t* __restrict__ y)
{
    const size_t i = ((size_t)blockIdx.x * 256 + threadIdx.x) * 8;
    float4 a = *(const float4*)(x + i);
    float4 b = *(const float4*)(x + i + 4);
    ushort_t o[8] = {f2b(a.x), f2b(a.y), f2b(a.z), f2b(a.w), f2b(b.x), f2b(b.y), f2b(b.z), f2b(b.w)};
    *(uint4*)( (void*)(y + i) ) = *(const uint4*)o;
}

__global__ __launch_bounds__(256)
void cast_mod_kernel(const float* __restrict__ m1, const float* __restrict__ m2,
                     ushort_t* __restrict__ h1, ushort_t* __restrict__ l1,
                     ushort_t* __restrict__ h2, ushort_t* __restrict__ l2)
{
    const float* x = blockIdx.y ? m2 : m1;
    ushort_t* yh = blockIdx.y ? h2 : h1;
    ushort_t* yl = blockIdx.y ? l2 : l1;
    const size_t i = ((size_t)blockIdx.x * 256 + threadIdx.x) * 8;
    float v[8];
    *(float4*)v = *(const float4*)(x + i);
    *(float4*)(v + 4) = *(const float4*)(x + i + 4);
    ushort_t oh[8], ol[8];
#pragma unroll
    for (int k = 0; k < 8; ++k) {
        oh[k] = f2b(v[k]);
        ol[k] = f2b(v[k] - b2f(oh[k]));
    }
    *(uint4*)( (void*)(yh + i) ) = *(const uint4*)oh;
    *(uint4*)( (void*)(yl + i) ) = *(const uint4*)ol;
}

// =================== weight transpose+cast: W[k][n] -> Wt[n][k] bf16 ======
struct WArgs {
    const float* src[8];
    ushort_t* hi[8];
    ushort_t* lo[8];
};
__global__ __launch_bounds__(256)
void wcast_kernel(WArgs args)
{
    __shared__ float T[64][65];
    const int z = blockIdx.z;
    const float* W = args.src[z];
    ushort_t* Th = args.hi[z];
    ushort_t* Tl = args.lo[z];
    const int k0 = blockIdx.x * 64, n0 = blockIdx.y * 64;
    const int tid = threadIdx.x;
    const int r = tid >> 2, cg = (tid & 3) * 16;
#pragma unroll
    for (int u = 0; u < 4; ++u) {
        float4 v = *(const float4*)(W + (size_t)(k0 + r) * 1024 + n0 + cg + u * 4);
        T[r][cg + u * 4 + 0] = v.x; T[r][cg + u * 4 + 1] = v.y;
        T[r][cg + u * 4 + 2] = v.z; T[r][cg + u * 4 + 3] = v.w;
    }
    __syncthreads();
    ushort_t oh[16], ol[16];
#pragma unroll
    for (int u = 0; u < 16; ++u) {
        float v = T[cg + u][r];
        oh[u] = f2b(v);
        ol[u] = f2b(v - b2f(oh[u]));
    }
    ushort_t* dh = Th + (size_t)(n0 + r) * 1024 + k0 + cg;
    *(uint4*)( (void*)dh ) = *(const uint4*)oh;
    *(uint4*)( (void*)(dh + 8) ) = *(const uint4*)(oh + 8);
    if (Tl) {
        ushort_t* dl = Tl + (size_t)(n0 + r) * 1024 + k0 + cg;
        *(uint4*)( (void*)dl ) = *(const uint4*)ol;
        *(uint4*)( (void*)(dl + 8) ) = *(const uint4*)(ol + 8);
    }
}

// =================== K norms (fp32) + cast K to bf16 ===================
__global__ __launch_bounds__(256)
void norms_cast_k_kernel(const float* __restrict__ K1f, const float* __restrict__ K2f,
                         ushort_t* __restrict__ K1b, ushort_t* __restrict__ K2b,
                         float* __restrict__ vv, float* __restrict__ aa, float* __restrict__ va)
{
    const int wave = threadIdx.x >> 6, lane = threadIdx.x & 63;
    const int row = blockIdx.x * 4 + wave;  // BHD*SK
    const float x1 = K1f[(size_t)row * 64 + lane];
    const float x2 = K2f[(size_t)row * 64 + lane];
    K1b[(size_t)row * 64 + lane] = f2b(x1);
    K2b[(size_t)row * 64 + lane] = f2b(x2);
    float s1 = x1 * x1, s2 = x2 * x2, s3 = x1 * x2;
#pragma unroll
    for (int o = 1; o < 64; o <<= 1) {
        s1 += __shfl_xor(s1, o);
        s2 += __shfl_xor(s2, o);
        s3 += __shfl_xor(s3, o);
    }
    if (lane == 0) { vv[row] = s1; aa[row] = s2; va[row] = s3; }
}

__global__ __launch_bounds__(256)
void normsq_kernel(const ushort_t* __restrict__ Qb, float* __restrict__ ll)
{
    const int wave = threadIdx.x >> 6, lane = threadIdx.x & 63;
    const int row = blockIdx.x * 4 + wave;  // BHD*LQ
    const float x = b2f(Qb[(size_t)row * 64 + lane]);
    float s = x * x;
#pragma unroll
    for (int o = 1; o < 64; o <<= 1) s += __shfl_xor(s, o);
    if (lane == 0) ll[row] = s;
}

// =================== V transpose: [bh][s][64] f32 -> [bh][64][1024] bf16 ===
__global__ __launch_bounds__(256)
void vtrans_kernel(const float* __restrict__ V1f, const float* __restrict__ V2f,
                   ushort_t* __restrict__ V1t, ushort_t* __restrict__ V2t)
{
    __shared__ float T[64][65];
    const float* Vf = blockIdx.z ? V2f : V1f;
    ushort_t* Vt = blockIdx.z ? V2t : V1t;
    const int bh = blockIdx.y, s0 = blockIdx.x * 64;
    const int tid = threadIdx.x;
    const int r = tid >> 2, cg = (tid & 3) * 16;
#pragma unroll
    for (int u = 0; u < 4; ++u) {
        float4 v = *(const float4*)(Vf + ((size_t)bh * 1024 + s0 + r) * 64 + cg + u * 4);
        T[r][cg + u * 4 + 0] = v.x; T[r][cg + u * 4 + 1] = v.y;
        T[r][cg + u * 4 + 2] = v.z; T[r][cg + u * 4 + 3] = v.w;
    }
    __syncthreads();
    ushort_t o[16];
#pragma unroll
    for (int u = 0; u < 16; ++u) o[u] = f2b(T[cg + u][r]);
    ushort_t* d = Vt + ((size_t)bh * 64 + r) * 1024 + s0 + cg;
    *(uint4*)( (void*)d ) = *(const uint4*)o;
    *(uint4*)( (void*)(d + 8) ) = *(const uint4*)(o + 8);
}

// =================== scores: logits = lv + la - 1.5*sqrt(det) =============
__global__ __launch_bounds__(256, 2)
void scores_kernel(const ushort_t* __restrict__ Qb, const ushort_t* __restrict__ K1b,
                   const ushort_t* __restrict__ K2b, const float* __restrict__ ll,
                   const float* __restrict__ vv, const float* __restrict__ aa,
                   const float* __restrict__ va, float* __restrict__ logits)
{
    __shared__ ushort_t Qs[128 * 64];
    __shared__ ushort_t K1s[128 * 64];
    __shared__ ushort_t K2s[128 * 64];
    __shared__ float llS[128], vvS[128], aaS[128], vaS[128];
    const int tid = threadIdx.x;
    const int wave = tid >> 6, lane = tid & 63;
    const int ln = lane & 15, lq = lane >> 4;
    const int wm = wave & 1, wn = wave >> 1;
    const int bh = blockIdx.z;
    const int l0 = blockIdx.y * 128, s0 = blockIdx.x * 128;
    const int cswz = (lane & 7) ^ ((lane >> 3) & 7);
    const int mrl = lane >> 3;

    if (tid < 128) {
        llS[tid] = ll[(size_t)bh * 512 + l0 + tid];
        vvS[tid] = vv[(size_t)bh * 1024 + s0 + tid];
        aaS[tid] = aa[(size_t)bh * 1024 + s0 + tid];
        vaS[tid] = va[(size_t)bh * 1024 + s0 + tid];
    }
#pragma unroll
    for (int j = 0; j < 4; ++j) {
        const int mr = (wave * 4 + j) * 8 + mrl;
        gload_lds16(Qb + ((size_t)bh * 512 + l0 + mr) * 64 + cswz * 8, (void*)(Qs + (wave * 4 + j) * 512));
        gload_lds16(K1b + ((size_t)bh * 1024 + s0 + mr) * 64 + cswz * 8, (void*)(K1s + (wave * 4 + j) * 512));
        gload_lds16(K2b + ((size_t)bh * 1024 + s0 + mr) * 64 + cswz * 8, (void*)(K2s + (wave * 4 + j) * 512));
    }
    __syncthreads();

    f32x4 zero = {0.f, 0.f, 0.f, 0.f};
    f32x4 lv[4][4], la[4][4];
#pragma unroll
    for (int i = 0; i < 4; ++i)
#pragma unroll
        for (int j = 0; j < 4; ++j) { lv[i][j] = zero; la[i][j] = zero; }

#pragma unroll
    for (int sub = 0; sub < 2; ++sub) {
        short8 qf[4], k1f[4], k2f[4];
#pragma unroll
        for (int i = 0; i < 4; ++i) {
            const int ml = wm * 64 + i * 16 + ln;
            qf[i] = *(const short8*)(Qs + ml * 64 + (((sub * 4 + lq) ^ (ml & 7)) * 8));
            const int nl = wn * 64 + i * 16 + ln;
            k1f[i] = *(const short8*)(K1s + nl * 64 + (((sub * 4 + lq) ^ (nl & 7)) * 8));
            k2f[i] = *(const short8*)(K2s + nl * 64 + (((sub * 4 + lq) ^ (nl & 7)) * 8));
        }
#pragma unroll
        for (int i = 0; i < 4; ++i)
#pragma unroll
            for (int j = 0; j < 4; ++j) {
                lv[i][j] = __builtin_amdgcn_mfma_f32_16x16x32_bf16(qf[i], k1f[j], lv[i][j], 0, 0, 0);
                la[i][j] = __builtin_amdgcn_mfma_f32_16x16x32_bf16(qf[i], k2f[j], la[i][j], 0, 0, 0);
            }
    }

#pragma unroll
    for (int i = 0; i < 4; ++i) {
#pragma unroll
        for (int r = 0; r < 4; ++r) {
            const int l_loc = wm * 64 + i * 16 + lq * 4 + r;
            const float LL = llS[l_loc];
#pragma unroll
            for (int j = 0; j < 4; ++j) {
                const int s_loc = wn * 64 + j * 16 + ln;
                const float VV = vvS[s_loc], AA = aaS[s_loc], VA = vaS[s_loc];
                const float LV = lv[i][j][r], LA = la[i][j][r];
                float det = LL * (VV * AA - VA * VA) - LV * (LV * AA - LA * VA) + LA * (LV * VA - LA * VV);
                det = fmaxf(det, 1e-8f);
                logits[((size_t)bh * 512 + l0 + l_loc) * 1024 + s0 + s_loc] = LV + LA - 1.5f * sqrtf(det);
            }
        }
    }
}

// =================== row softmax, fp32 in -> bf16 out (in place) ==========
__global__ __launch_bounds__(256)
void softmax_kernel(float* __restrict__ logits)
{
    const size_t row = blockIdx.x;
    const float4* p = (const float4*)(logits + row * 1024);
    float4 v = p[threadIdx.x];
    const int wave = threadIdx.x >> 6, lane = threadIdx.x & 63;
    __shared__ float redm[4], reds[4];
    float m = fmaxf(fmaxf(v.x, v.y), fmaxf(v.z, v.w));
#pragma unroll
    for (int o = 1; o < 64; o <<= 1) m = fmaxf(m, __shfl_xor(m, o));
    if (lane == 0) redm[wave] = m;
    __syncthreads();
    m = fmaxf(fmaxf(redm[0], redm[1]), fmaxf(redm[2], redm[3]));
    v.x = __expf(v.x - m); v.y = __expf(v.y - m);
    v.z = __expf(v.z - m); v.w = __expf(v.w - m);
    float s = v.x + v.y + v.z + v.w;
#pragma unroll
    for (int o = 1; o < 64; o <<= 1) s += __shfl_xor(s, o);
    if (lane == 0) reds[wave] = s;
    __syncthreads();
    s = reds[0] + reds[1] + reds[2] + reds[3];
    const float inv = 1.0f / s;
    ushort_t w[4] = {f2b(v.x * inv), f2b(v.y * inv), f2b(v.z * inv), f2b(v.w * inv)};
    ushort_t* attnRow = (ushort_t*)(logits + row * 1024);  // bf16 packed in row's own slot
    *(uint2*)( (void*)(attnRow + threadIdx.x * 4) ) = *(const uint2*)w;
}

// =================== mean over heads -> avg_weights [B][L][S] ==============
__global__ __launch_bounds__(256)
void head_avg_kernel(const ushort_t* __restrict__ attn, float* __restrict__ outv)
{
    const int idx = blockIdx.x * 256 + threadIdx.x;  // B*L*S/8
    const int s8 = idx & 127;
    const int l = (idx >> 7) & 511;
    const int b = idx >> 16;
    float acc[8] = {};
#pragma unroll
    for (int h = 0; h < 16; ++h) {
        const ushort_t* p = attn + ((size_t)((b * 16 + h) * 512 + l)) * 2048 + s8 * 8;
        uint4 u = *(const uint4*)p;
        const uint_t uu[4] = {u.x, u.y, u.z, u.w};
#pragma unroll
        for (int q = 0; q < 4; ++q) {
            acc[2 * q]     += __uint_as_float((uu[q] & 0xffffu) << 16);
            acc[2 * q + 1] += __uint_as_float(uu[q] & 0xffff0000u);
        }
    }
    float* d = outv + (size_t)idx * 8;
    float4 o1 = {acc[0] * 0.0625f, acc[1] * 0.0625f, acc[2] * 0.0625f, acc[3] * 0.0625f};
    float4 o2 = {acc[4] * 0.0625f, acc[5] * 0.0625f, acc[6] * 0.0625f, acc[7] * 0.0625f};
    *(float4*)d = o1;
    *(float4*)(d + 4) = o2;
}

// =================== PV (v1,v2) + gating -> tmp bf16 [t][E] ================
__global__ __launch_bounds__(256, 2)
void pv_gate_kernel(const ushort_t* __restrict__ attn, const ushort_t* __restrict__ V1t,
                    const ushort_t* __restrict__ V2t, const float* __restrict__ G1,
                    const float* __restrict__ G2, ushort_t* __restrict__ tmpb)
{
    __shared__ ushort_t Ps[128 * 64];
    __shared__ ushort_t V1s[64 * 64];
    __shared__ ushort_t V2s[64 * 64];
    const int tid = threadIdx.x;
    const int wave = tid >> 6, lane = tid & 63;
    const int ln = lane & 15, lq = lane >> 4;
    const int bh = blockIdx.y;
    const int l0 = blockIdx.x * 128;
    const int cswz = (lane & 7) ^ ((lane >> 3) & 7);
    const int mrl = lane >> 3;
    const int bq = bh >> 4, h = bh & 15;

    f32x4 zero = {0.f, 0.f, 0.f, 0.f};
    f32x4 acc1[2][4], acc2[2][4];
#pragma unroll
    for (int i = 0; i < 2; ++i)
#pragma unroll
        for (int j = 0; j < 4; ++j) { acc1[i][j] = zero; acc2[i][j] = zero; }

    for (int s0 = 0; s0 < 1024; s0 += 64) {
        __syncthreads();
#pragma unroll
        for (int j = 0; j < 4; ++j) {
            const int mr = (wave * 4 + j) * 8 + mrl;
            gload_lds16(attn + ((size_t)bh * 512 + l0 + mr) * 2048 + s0 + cswz * 8,
                        (void*)(Ps + (wave * 4 + j) * 512));
        }
#pragma unroll
        for (int j = 0; j < 2; ++j) {
            const int mv = (wave * 2 + j) * 8 + mrl;
            gload_lds16(V1t + ((size_t)bh * 64 + mv) * 1024 + s0 + cswz * 8,
                        (void*)(V1s + (wave * 2 + j) * 512));
            gload_lds16(V2t + ((size_t)bh * 64 + mv) * 1024 + s0 + cswz * 8,
                        (void*)(V2s + (wave * 2 + j) * 512));
        }
        __syncthreads();
#pragma unroll
        for (int sub = 0; sub < 2; ++sub) {
            short8 af[2], b1f[4], b2f_[4];
#pragma unroll
            for (int i = 0; i < 2; ++i) {
                const int ml = wave * 32 + i * 16 + ln;
                af[i] = *(const short8*)(Ps + ml * 64 + (((sub * 4 + lq) ^ (ml & 7)) * 8));
            }
#pragma unroll
            for (int j = 0; j < 4; ++j) {
                const int nl = j * 16 + ln;
                b1f[j] = *(const short8*)(V1s + nl * 64 + (((sub * 4 + lq) ^ (nl & 7)) * 8));
                b2f_[j] = *(const short8*)(V2s + nl * 64 + (((sub * 4 + lq) ^ (nl & 7)) * 8));
            }
#pragma unroll
            for (int i = 0; i < 2; ++i)
#pragma unroll
                for (int j = 0; j < 4; ++j) {
                    acc1[i][j] = __builtin_amdgcn_mfma_f32_16x16x32_bf16(af[i], b1f[j], acc1[i][j], 0, 0, 0);
                    acc2[i][j] = __builtin_amdgcn_mfma_f32_16x16x32_bf16(af[i], b2f_[j], acc2[i][j], 0, 0, 0);
                }
        }
    }

#pragma unroll
    for (int i = 0; i < 2; ++i) {
#pragma unroll
        for (int r = 0; r < 4; ++r) {
            const int l = l0 + wave * 32 + i * 16 + lq * 4 + r;
#pragma unroll
            for (int j = 0; j < 4; ++j) {
                const int d = j * 16 + ln;
                const size_t addr = ((size_t)l * 4 + bq) * 1024 + h * 64 + d;
                const float v = 0.5f * (acc1[i][j][r] * G1[addr] + acc2[i][j][r] * G2[addr]);
                tmpb[addr] = f2b(v);
            }
        }
    }
}

// ============================ launch ============================
extern "C" void kernel_launch(void* const* d_in, const int* in_sizes, int n_in,
                              void* d_out, int out_size, void* d_ws, size_t ws_size,
                              hipStream_t stream)
{
    const float* query = (const float*)d_in[0];
    const float* mod1  = (const float*)d_in[1];
    const float* mod2  = (const float*)d_in[2];
    const float* q_w  = (const float*)d_in[3];  const float* q_b  = (const float*)d_in[4];
    const float* k1_w = (const float*)d_in[5];  const float* k1_b = (const float*)d_in[6];
    const float* k2_w = (const float*)d_in[7];  const float* k2_b = (const float*)d_in[8];
    const float* v1_w = (const float*)d_in[9];  const float* v1_b = (const float*)d_in[10];
    const float* v2_w = (const float*)d_in[11]; const float* v2_b = (const float*)d_in[12];
    const float* g1_w = (const float*)d_in[13]; const float* g1_b = (const float*)d_in[14];
    const float* g2_w = (const float*)d_in[15]; const float* g2_b = (const float*)d_in[16];
    const float* o_w  = (const float*)d_in[17]; const float* o_b  = (const float*)d_in[18];
    float* out = (float*)d_out;

    const size_t MB = 1u << 20;
    char* w = (char*)d_ws;
    ushort_t* Wq   = (ushort_t*)(w + 0 * MB);
    ushort_t* Wv1  = (ushort_t*)(w + 2 * MB);
    ushort_t* Wv2  = (ushort_t*)(w + 4 * MB);
    ushort_t* Wg1  = (ushort_t*)(w + 6 * MB);
    ushort_t* Wg2  = (ushort_t*)(w + 8 * MB);
    ushort_t* Wo   = (ushort_t*)(w + 10 * MB);
    ushort_t* Wk1h = (ushort_t*)(w + 12 * MB);
    ushort_t* Wk1l = (ushort_t*)(w + 14 * MB);
    ushort_t* Wk2h = (ushort_t*)(w + 16 * MB);
    ushort_t* Wk2l = (ushort_t*)(w + 18 * MB);
    ushort_t* qx   = (ushort_t*)(w + 20 * MB);   // dead after q/g gemms
    ushort_t* tmpb = qx;                         // reused for gated PV output
    ushort_t* m1h  = (ushort_t*)(w + 24 * MB);   // X region, dead after proj gemms
    ushort_t* m1l  = (ushort_t*)(w + 32 * MB);
    ushort_t* m2h  = (ushort_t*)(w + 40 * MB);
    ushort_t* m2l  = (ushort_t*)(w + 48 * MB);
    ushort_t* K1b  = (ushort_t*)(w + 24 * MB);   // overlays X region
    ushort_t* K2b  = (ushort_t*)(w + 32 * MB);
    ushort_t* V1t  = (ushort_t*)(w + 40 * MB);
    ushort_t* V2t  = (ushort_t*)(w + 48 * MB);
    float* G1 = (float*)(w + 56 * MB);
    float* G2 = (float*)(w + 64 * MB);
    ushort_t* Qb = (ushort_t*)(w + 72 * MB);
    float* ll = (float*)(w + 76 * MB);
    float* vv = (float*)(w + 76 * MB + 131072);
    float* aa = (float*)(w + 76 * MB + 393216);
    float* va = (float*)(w + 76 * MB + 655360);
    float* logits = (float*)(w + 78 * MB);       // 128MB
    float* K1f = (float*)(w + 78 * MB);          // overlay inside logits region
    float* K2f = (float*)(w + 94 * MB);
    float* V1f = (float*)(w + 110 * MB);
    float* V2f = (float*)(w + 126 * MB);
    ushort_t* attn = (ushort_t*)logits;          // bf16, row stride 2048 elems

    // casts
    cast_q_kernel<<<1024, 256, 0, stream>>>(query, qx);
    cast_mod_kernel<<<dim3(2048, 2), 256, 0, stream>>>(mod1, mod2, m1h, m1l, m2h, m2l);
    WArgs wa;
    const float* srcs[8] = {q_w, v1_w, v2_w, g1_w, g2_w, o_w, k1_w, k2_w};
    ushort_t* his[8] = {Wq, Wv1, Wv2, Wg1, Wg2, Wo, Wk1h, Wk2h};
    ushort_t* los[8] = {nullptr, nullptr, nullptr, nullptr, nullptr, nullptr, Wk1l, Wk2l};
    for (int i = 0; i < 8; ++i) { wa.src[i] = srcs[i]; wa.hi[i] = his[i]; wa.lo[i] = los[i]; }
    wcast_kernel<<<dim3(16, 16, 8), 256, 0, stream>>>(wa);

    // projections (bf16 MFMA; k1/k2 in split precision)
    gemm_mfma<2, 0><<<dim3(8, 16), 256, 0, stream>>>(qx, nullptr, Wq, nullptr, q_b, Qb, 512, 0.125f);
    gemm_mfma<1, 1><<<dim3(8, 32), 256, 0, stream>>>(m1h, m1l, Wk1h, Wk1l, k1_b, K1f, 1024, 1.f);
    gemm_mfma<1, 1><<<dim3(8, 32), 256, 0, stream>>>(m2h, m2l, Wk2h, Wk2l, k2_b, K2f, 1024, 1.f);
    gemm_mfma<1, 0><<<dim3(8, 32), 256, 0, stream>>>(m1h, nullptr, Wv1, nullptr, v1_b, V1f, 1024, 1.f);
    gemm_mfma<1, 0><<<dim3(8, 32), 256, 0, stream>>>(m2h, nullptr, Wv2, nullptr, v2_b, V2f, 1024, 1.f);
    gemm_mfma<3, 0><<<dim3(8, 16), 256, 0, stream>>>(qx, nullptr, Wg1, nullptr, g1_b, G1, 0, 1.f);
    gemm_mfma<3, 0><<<dim3(8, 16), 256, 0, stream>>>(qx, nullptr, Wg2, nullptr, g2_b, G2, 0, 1.f);

    // norms + bf16 casts + V transpose
    norms_cast_k_kernel<<<16384, 256, 0, stream>>>(K1f, K2f, K1b, K2b, vv, aa, va);
    normsq_kernel<<<8192, 256, 0, stream>>>(Qb, ll);
    vtrans_kernel<<<dim3(16, 64, 2), 256, 0, stream>>>(V1f, V2f, V1t, V2t);

    // attention
    scores_kernel<<<dim3(8, 4, 64), 256, 0, stream>>>(Qb, K1b, K2b, ll, vv, aa, va, logits);
    softmax_kernel<<<32768, 256, 0, stream>>>(logits);
    head_avg_kernel<<<1024, 256, 0, stream>>>(attn, out + (size_t)LQ * NB * EDIM);
    pv_gate_kernel<<<dim3(4, 64), 256, 0, stream>>>(attn, V1t, V2t, G1, G2, tmpb);

    // output projection
    gemm_mfma<0, 0><<<dim3(8, 16), 256, 0, stream>>>(tmpb, nullptr, Wo, nullptr, o_b, out, 0, 1.f);
}

// Round 4
// 436.071 us; speedup vs baseline: 3.1874x; 1.1786x over previous
//
#include <hip/hip_runtime.h>
#include <cstddef>
#include <cstdint>

typedef unsigned short ushort_t;
typedef unsigned int uint_t;
typedef __attribute__((ext_vector_type(8))) short short8;
typedef __attribute__((ext_vector_type(4))) float f32x4;

#define EDIM 1024
#define NHEAD 16
#define HDIM 64
#define NB 4
#define LQ 512
#define SK 1024
#define BHD 64

__device__ __forceinline__ ushort_t f2b(float f) {
    uint_t u = __float_as_uint(f);
    return (ushort_t)((u + 0x7fffu + ((u >> 16) & 1u)) >> 16);
}
__device__ __forceinline__ float b2f(ushort_t b) {
    return __uint_as_float(((uint_t)b) << 16);
}

__device__ __forceinline__ void gload_lds16(const void* g, void* l) {
    __builtin_amdgcn_global_load_lds((const __attribute__((address_space(1))) void*)g,
                                     (__attribute__((address_space(3))) void*)l, 16, 0, 0);
}

// =================== bf16 MFMA GEMM, 128x128 tile, K=1024 ===================
// A [M][1024] bf16 row-major ; B [N][1024] bf16 (pre-transposed, n-major)
// OUTMODE 0: fp32 [row][1024] + b0                                  (o-proj)
// OUTMODE 4: seg0 -> Qb bf16 head-split *scale; seg1/2 -> G1/G2 fp32 sigmoid
// OUTMODE 5: seg0 -> K fp32 head-split, SPLIT-PRECISION (3-pass hi/lo);
//            seg1 -> V bf16 head-split (1 pass)
template<int OUTMODE>
__global__ __launch_bounds__(256, 2)
void gemm_mfma(const ushort_t* __restrict__ Ah, const ushort_t* __restrict__ Al,
               const ushort_t* __restrict__ Bh, const ushort_t* __restrict__ Bl,
               const float* __restrict__ b0, const float* __restrict__ b1,
               const float* __restrict__ b2,
               void* __restrict__ Y0, void* __restrict__ Y1, void* __restrict__ Y2,
               float scale)
{
    __shared__ ushort_t As[128 * 64];
    __shared__ ushort_t Bs[128 * 64];
    const int tid = threadIdx.x;
    const int wave = tid >> 6, lane = tid & 63;
    const int ln = lane & 15, lq = lane >> 4;
    const int row0 = blockIdx.y * 128, col0 = blockIdx.x * 128;
    const int wm = wave & 1, wn = wave >> 1;
    const int cswz = (lane & 7) ^ ((lane >> 3) & 7);
    const int mrl = lane >> 3;

    const int seg = (OUTMODE == 0) ? 0 : (blockIdx.x >> 3);
    const int NPASS = (OUTMODE == 5 && seg == 0) ? 3 : 1;

    f32x4 zero = {0.f, 0.f, 0.f, 0.f};
    f32x4 acc[4][4];
#pragma unroll
    for (int i = 0; i < 4; ++i)
#pragma unroll
        for (int j = 0; j < 4; ++j) acc[i][j] = zero;

    for (int pp = 0; pp < NPASS; ++pp) {
        const ushort_t* Ab = (pp == 2) ? Al : Ah;   // AhBh + AhBl + AlBh
        const ushort_t* Bb = (pp == 1) ? Bl : Bh;
        for (int kk = 0; kk < 1024; kk += 64) {
            __syncthreads();
#pragma unroll
            for (int j = 0; j < 4; ++j) {
                const int mr = (wave * 4 + j) * 8 + mrl;
                gload_lds16(Ab + (size_t)(row0 + mr) * 1024 + kk + cswz * 8,
                            (void*)(As + (wave * 4 + j) * 512));
                gload_lds16(Bb + (size_t)(col0 + mr) * 1024 + kk + cswz * 8,
                            (void*)(Bs + (wave * 4 + j) * 512));
            }
            __syncthreads();
#pragma unroll
            for (int sub = 0; sub < 2; ++sub) {
                short8 af[4], bfv[4];
#pragma unroll
                for (int i = 0; i < 4; ++i) {
                    const int ml = wm * 64 + i * 16 + ln;
                    af[i] = *(const short8*)(As + ml * 64 + (((sub * 4 + lq) ^ (ml & 7)) * 8));
                    const int nl = wn * 64 + i * 16 + ln;
                    bfv[i] = *(const short8*)(Bs + nl * 64 + (((sub * 4 + lq) ^ (nl & 7)) * 8));
                }
#pragma unroll
                for (int i = 0; i < 4; ++i)
#pragma unroll
                    for (int j = 0; j < 4; ++j)
                        acc[i][j] = __builtin_amdgcn_mfma_f32_16x16x32_bf16(af[i], bfv[j], acc[i][j], 0, 0, 0);
            }
        }
    }

    const float* bias = (seg == 0) ? b0 : ((seg == 1) ? b1 : b2);

#pragma unroll
    for (int i = 0; i < 4; ++i) {
#pragma unroll
        for (int r = 0; r < 4; ++r) {
            const int row = row0 + wm * 64 + i * 16 + lq * 4 + r;
#pragma unroll
            for (int j = 0; j < 4; ++j) {
                const int col = col0 + wn * 64 + j * 16 + ln;
                const int lc = col & 1023;
                float v = acc[i][j][r] + bias[lc];
                if (OUTMODE == 0) {
                    ((float*)Y0)[(size_t)row * 1024 + lc] = v;
                } else if (OUTMODE == 4) {
                    if (seg == 0) {
                        v *= scale;
                        const int s = row >> 2, b = row & 3, h = lc >> 6, d = lc & 63;
                        ((ushort_t*)Y0)[(((size_t)(b * 16 + h)) * 512 + s) * 64 + d] = f2b(v);
                    } else {
                        v = 1.0f / (1.0f + __expf(-v));
                        float* Y = (seg == 1) ? (float*)Y1 : (float*)Y2;
                        Y[(size_t)row * 1024 + lc] = v;
                    }
                } else {  // OUTMODE 5
                    const int s = row >> 2, b = row & 3, h = lc >> 6, d = lc & 63;
                    const size_t addr = (((size_t)(b * 16 + h)) * 1024 + s) * 64 + d;
                    if (seg == 0) ((float*)Y0)[addr] = v;       // K fp32 (for norms)
                    else          ((ushort_t*)Y1)[addr] = f2b(v);  // V bf16
                }
            }
        }
    }
}

// =================== input casts ===================
__global__ __launch_bounds__(256)
void cast_q_kernel(const float* __restrict__ x, ushort_t* __restrict__ y)
{
    const size_t i = ((size_t)blockIdx.x * 256 + threadIdx.x) * 8;
    float4 a = *(const float4*)(x + i);
    float4 b = *(const float4*)(x + i + 4);
    ushort_t o[8] = {f2b(a.x), f2b(a.y), f2b(a.z), f2b(a.w), f2b(b.x), f2b(b.y), f2b(b.z), f2b(b.w)};
    *(uint4*)( (void*)(y + i) ) = *(const uint4*)o;
}

// hi+lo split cast for mod inputs (feeds split-precision K GEMM)
__global__ __launch_bounds__(256)
void cast_mod_kernel(const float* __restrict__ m1, const float* __restrict__ m2,
                     ushort_t* __restrict__ h1, ushort_t* __restrict__ l1,
                     ushort_t* __restrict__ h2, ushort_t* __restrict__ l2)
{
    const float* x = blockIdx.y ? m2 : m1;
    ushort_t* yh = blockIdx.y ? h2 : h1;
    ushort_t* yl = blockIdx.y ? l2 : l1;
    const size_t i = ((size_t)blockIdx.x * 256 + threadIdx.x) * 8;
    float v[8];
    *(float4*)v = *(const float4*)(x + i);
    *(float4*)(v + 4) = *(const float4*)(x + i + 4);
    ushort_t oh[8], ol[8];
#pragma unroll
    for (int k = 0; k < 8; ++k) {
        oh[k] = f2b(v[k]);
        ol[k] = f2b(v[k] - b2f(oh[k]));
    }
    *(uint4*)( (void*)(yh + i) ) = *(const uint4*)oh;
    *(uint4*)( (void*)(yl + i) ) = *(const uint4*)ol;
}

// ====== weight transpose+cast: W[k][n] fp32 -> Wt[n][k] bf16 (hi, opt lo) ==
struct WArgs {
    const float* src[8];
    ushort_t* hi[8];
    ushort_t* lo[8];
};
__global__ __launch_bounds__(256)
void wcast_kernel(WArgs args)
{
    __shared__ float T[64][65];
    const int z = blockIdx.z;
    const float* W = args.src[z];
    ushort_t* Th = args.hi[z];
    ushort_t* Tl = args.lo[z];
    const int k0 = blockIdx.x * 64, n0 = blockIdx.y * 64;
    const int tid = threadIdx.x;
    const int r = tid >> 2, cg = (tid & 3) * 16;
#pragma unroll
    for (int u = 0; u < 4; ++u) {
        float4 v = *(const float4*)(W + (size_t)(k0 + r) * 1024 + n0 + cg + u * 4);
        T[r][cg + u * 4 + 0] = v.x; T[r][cg + u * 4 + 1] = v.y;
        T[r][cg + u * 4 + 2] = v.z; T[r][cg + u * 4 + 3] = v.w;
    }
    __syncthreads();
    ushort_t oh[16], ol[16];
#pragma unroll
    for (int u = 0; u < 16; ++u) {
        float v = T[cg + u][r];
        oh[u] = f2b(v);
        ol[u] = f2b(v - b2f(oh[u]));
    }
    ushort_t* dh = Th + (size_t)(n0 + r) * 1024 + k0 + cg;
    *(uint4*)( (void*)dh ) = *(const uint4*)oh;
    *(uint4*)( (void*)(dh + 8) ) = *(const uint4*)(oh + 8);
    if (Tl) {
        ushort_t* dl = Tl + (size_t)(n0 + r) * 1024 + k0 + cg;
        *(uint4*)( (void*)dl ) = *(const uint4*)ol;
        *(uint4*)( (void*)(dl + 8) ) = *(const uint4*)(ol + 8);
    }
}

// ======== K norms (fp32 from fp32 K) + cast K to bf16 for MFMA ========
__global__ __launch_bounds__(256)
void norms_cast_k_kernel(const float* __restrict__ K1f, const float* __restrict__ K2f,
                         ushort_t* __restrict__ K1b, ushort_t* __restrict__ K2b,
                         float* __restrict__ vv, float* __restrict__ aa, float* __restrict__ va)
{
    const int wave = threadIdx.x >> 6, lane = threadIdx.x & 63;
    const int row = blockIdx.x * 4 + wave;  // BHD*SK
    const float x1 = K1f[(size_t)row * 64 + lane];
    const float x2 = K2f[(size_t)row * 64 + lane];
    K1b[(size_t)row * 64 + lane] = f2b(x1);
    K2b[(size_t)row * 64 + lane] = f2b(x2);
    float s1 = x1 * x1, s2 = x2 * x2, s3 = x1 * x2;
#pragma unroll
    for (int o = 1; o < 64; o <<= 1) {
        s1 += __shfl_xor(s1, o);
        s2 += __shfl_xor(s2, o);
        s3 += __shfl_xor(s3, o);
    }
    if (lane == 0) { vv[row] = s1; aa[row] = s2; va[row] = s3; }
}

__global__ __launch_bounds__(256)
void normsq_kernel(const ushort_t* __restrict__ Qb, float* __restrict__ ll)
{
    const int wave = threadIdx.x >> 6, lane = threadIdx.x & 63;
    const int row = blockIdx.x * 4 + wave;  // BHD*LQ
    const float x = b2f(Qb[(size_t)row * 64 + lane]);
    float s = x * x;
#pragma unroll
    for (int o = 1; o < 64; o <<= 1) s += __shfl_xor(s, o);
    if (lane == 0) ll[row] = s;
}

// ====== V transpose: [bh][s][64] bf16 -> [bh][64][1024] bf16 ======
__global__ __launch_bounds__(256)
void vtrans_kernel(const ushort_t* __restrict__ V1b, const ushort_t* __restrict__ V2b,
                   ushort_t* __restrict__ V1t, ushort_t* __restrict__ V2t)
{
    __shared__ float T[64][65];
    const ushort_t* S = blockIdx.z ? V2b : V1b;
    ushort_t* D = blockIdx.z ? V2t : V1t;
    const int bh = blockIdx.y, s0 = blockIdx.x * 64;
    const int tid = threadIdx.x;
    const int r = tid >> 2, cg = (tid & 3) * 16;
    ushort_t buf[16];
    const ushort_t* sp = S + ((size_t)bh * 1024 + s0 + r) * 64 + cg;
    *(uint4*)buf = *(const uint4*)sp;
    *(uint4*)(buf + 8) = *(const uint4*)(sp + 8);
#pragma unroll
    for (int u = 0; u < 16; ++u) T[r][cg + u] = b2f(buf[u]);
    __syncthreads();
    ushort_t o[16];
#pragma unroll
    for (int u = 0; u < 16; ++u) o[u] = f2b(T[cg + u][r]);
    ushort_t* d = D + ((size_t)bh * 64 + r) * 1024 + s0 + cg;
    *(uint4*)( (void*)d ) = *(const uint4*)o;
    *(uint4*)( (void*)(d + 8) ) = *(const uint4*)(o + 8);
}

// =================== scores: logits = lv + la - 1.5*sqrt(det) =============
__global__ __launch_bounds__(256, 2)
void scores_kernel(const ushort_t* __restrict__ Qb, const ushort_t* __restrict__ K1b,
                   const ushort_t* __restrict__ K2b, const float* __restrict__ ll,
                   const float* __restrict__ vv, const float* __restrict__ aa,
                   const float* __restrict__ va, float* __restrict__ logits)
{
    __shared__ ushort_t Qs[128 * 64];
    __shared__ ushort_t K1s[128 * 64];
    __shared__ ushort_t K2s[128 * 64];
    __shared__ float llS[128], vvS[128], aaS[128], vaS[128];
    const int tid = threadIdx.x;
    const int wave = tid >> 6, lane = tid & 63;
    const int ln = lane & 15, lq = lane >> 4;
    const int wm = wave & 1, wn = wave >> 1;
    const int bh = blockIdx.z;
    const int l0 = blockIdx.y * 128, s0 = blockIdx.x * 128;
    const int cswz = (lane & 7) ^ ((lane >> 3) & 7);
    const int mrl = lane >> 3;

    if (tid < 128) {
        llS[tid] = ll[(size_t)bh * 512 + l0 + tid];
        vvS[tid] = vv[(size_t)bh * 1024 + s0 + tid];
        aaS[tid] = aa[(size_t)bh * 1024 + s0 + tid];
        vaS[tid] = va[(size_t)bh * 1024 + s0 + tid];
    }
#pragma unroll
    for (int j = 0; j < 4; ++j) {
        const int mr = (wave * 4 + j) * 8 + mrl;
        gload_lds16(Qb + ((size_t)bh * 512 + l0 + mr) * 64 + cswz * 8, (void*)(Qs + (wave * 4 + j) * 512));
        gload_lds16(K1b + ((size_t)bh * 1024 + s0 + mr) * 64 + cswz * 8, (void*)(K1s + (wave * 4 + j) * 512));
        gload_lds16(K2b + ((size_t)bh * 1024 + s0 + mr) * 64 + cswz * 8, (void*)(K2s + (wave * 4 + j) * 512));
    }
    __syncthreads();

    f32x4 zero = {0.f, 0.f, 0.f, 0.f};
    f32x4 lv[4][4], la[4][4];
#pragma unroll
    for (int i = 0; i < 4; ++i)
#pragma unroll
        for (int j = 0; j < 4; ++j) { lv[i][j] = zero; la[i][j] = zero; }

#pragma unroll
    for (int sub = 0; sub < 2; ++sub) {
        short8 qf[4], k1f[4], k2f[4];
#pragma unroll
        for (int i = 0; i < 4; ++i) {
            const int ml = wm * 64 + i * 16 + ln;
            qf[i] = *(const short8*)(Qs + ml * 64 + (((sub * 4 + lq) ^ (ml & 7)) * 8));
            const int nl = wn * 64 + i * 16 + ln;
            k1f[i] = *(const short8*)(K1s + nl * 64 + (((sub * 4 + lq) ^ (nl & 7)) * 8));
            k2f[i] = *(const short8*)(K2s + nl * 64 + (((sub * 4 + lq) ^ (nl & 7)) * 8));
        }
#pragma unroll
        for (int i = 0; i < 4; ++i)
#pragma unroll
            for (int j = 0; j < 4; ++j) {
                lv[i][j] = __builtin_amdgcn_mfma_f32_16x16x32_bf16(qf[i], k1f[j], lv[i][j], 0, 0, 0);
                la[i][j] = __builtin_amdgcn_mfma_f32_16x16x32_bf16(qf[i], k2f[j], la[i][j], 0, 0, 0);
            }
    }

#pragma unroll
    for (int i = 0; i < 4; ++i) {
#pragma unroll
        for (int r = 0; r < 4; ++r) {
            const int l_loc = wm * 64 + i * 16 + lq * 4 + r;
            const float LL = llS[l_loc];
#pragma unroll
            for (int j = 0; j < 4; ++j) {
                const int s_loc = wn * 64 + j * 16 + ln;
                const float VV = vvS[s_loc], AA = aaS[s_loc], VA = vaS[s_loc];
                const float LV = lv[i][j][r], LA = la[i][j][r];
                float det = LL * (VV * AA - VA * VA) - LV * (LV * AA - LA * VA) + LA * (LV * VA - LA * VV);
                det = fmaxf(det, 1e-8f);
                logits[((size_t)bh * 512 + l0 + l_loc) * 1024 + s0 + s_loc] = LV + LA - 1.5f * sqrtf(det);
            }
        }
    }
}

// ======= softmax (fp32 -> bf16 in place) fused with head-average ==========
__global__ __launch_bounds__(256)
void softmax_avg_kernel(float* __restrict__ logits, float* __restrict__ avg)
{
    __shared__ float part[4][1024];
    const int b = blockIdx.x >> 9, l = blockIdx.x & 511;
    const int wave = threadIdx.x >> 6, lane = threadIdx.x & 63;
    float pacc[16];
#pragma unroll
    for (int u = 0; u < 16; ++u) pacc[u] = 0.f;
#pragma unroll
    for (int jj = 0; jj < 4; ++jj) {
        const int h = wave * 4 + jj;
        float* rowp = logits + (((size_t)(b * 16 + h)) * 512 + l) * 1024;
        float4 v[4];
#pragma unroll
        for (int c = 0; c < 4; ++c) v[c] = *(const float4*)(rowp + c * 256 + lane * 4);
        float m = -3.4e38f;
#pragma unroll
        for (int c = 0; c < 4; ++c) m = fmaxf(m, fmaxf(fmaxf(v[c].x, v[c].y), fmaxf(v[c].z, v[c].w)));
#pragma unroll
        for (int o = 1; o < 64; o <<= 1) m = fmaxf(m, __shfl_xor(m, o));
        float s = 0.f;
#pragma unroll
        for (int c = 0; c < 4; ++c) {
            v[c].x = __expf(v[c].x - m); v[c].y = __expf(v[c].y - m);
            v[c].z = __expf(v[c].z - m); v[c].w = __expf(v[c].w - m);
            s += v[c].x + v[c].y + v[c].z + v[c].w;
        }
#pragma unroll
        for (int o = 1; o < 64; o <<= 1) s += __shfl_xor(s, o);
        const float inv = 1.0f / s;
        ushort_t* arow = (ushort_t*)rowp;
#pragma unroll
        for (int c = 0; c < 4; ++c) {
            const float p0 = v[c].x * inv, p1 = v[c].y * inv, p2 = v[c].z * inv, p3 = v[c].w * inv;
            ushort_t w[4] = {f2b(p0), f2b(p1), f2b(p2), f2b(p3)};
            *(uint2*)( (void*)(arow + c * 256 + lane * 4) ) = *(const uint2*)w;
            pacc[c * 4 + 0] += p0; pacc[c * 4 + 1] += p1;
            pacc[c * 4 + 2] += p2; pacc[c * 4 + 3] += p3;
        }
    }
#pragma unroll
    for (int c = 0; c < 4; ++c) {
        float4 pv = {pacc[c * 4 + 0], pacc[c * 4 + 1], pacc[c * 4 + 2], pacc[c * 4 + 3]};
        *(float4*)(&part[wave][c * 256 + lane * 4]) = pv;
    }
    __syncthreads();
    const int s0 = threadIdx.x * 4;
    float4 a0 = *(const float4*)(&part[0][s0]);
    float4 a1 = *(const float4*)(&part[1][s0]);
    float4 a2 = *(const float4*)(&part[2][s0]);
    float4 a3 = *(const float4*)(&part[3][s0]);
    float4 o;
    o.x = (a0.x + a1.x + a2.x + a3.x) * 0.0625f;
    o.y = (a0.y + a1.y + a2.y + a3.y) * 0.0625f;
    o.z = (a0.z + a1.z + a2.z + a3.z) * 0.0625f;
    o.w = (a0.w + a1.w + a2.w + a3.w) * 0.0625f;
    *(float4*)(avg + ((size_t)(b * 512 + l)) * 1024 + s0) = o;
}

// =================== PV (v1,v2) + gating -> tmp bf16 [t][E] ================
__global__ __launch_bounds__(256, 2)
void pv_gate_kernel(const ushort_t* __restrict__ attn, const ushort_t* __restrict__ V1t,
                    const ushort_t* __restrict__ V2t, const float* __restrict__ G1,
                    const float* __restrict__ G2, ushort_t* __restrict__ tmpb)
{
    __shared__ ushort_t Ps[128 * 64];
    __shared__ ushort_t V1s[64 * 64];
    __shared__ ushort_t V2s[64 * 64];
    const int tid = threadIdx.x;
    const int wave = tid >> 6, lane = tid & 63;
    const int ln = lane & 15, lq = lane >> 4;
    const int bh = blockIdx.y;
    const int l0 = blockIdx.x * 128;
    const int cswz = (lane & 7) ^ ((lane >> 3) & 7);
    const int mrl = lane >> 3;
    const int bq = bh >> 4, h = bh & 15;

    f32x4 zero = {0.f, 0.f, 0.f, 0.f};
    f32x4 acc1[2][4], acc2[2][4];
#pragma unroll
    for (int i = 0; i < 2; ++i)
#pragma unroll
        for (int j = 0; j < 4; ++j) { acc1[i][j] = zero; acc2[i][j] = zero; }

    for (int s0 = 0; s0 < 1024; s0 += 64) {
        __syncthreads();
#pragma unroll
        for (int j = 0; j < 4; ++j) {
            const int mr = (wave * 4 + j) * 8 + mrl;
            gload_lds16(attn + ((size_t)bh * 512 + l0 + mr) * 2048 + s0 + cswz * 8,
                        (void*)(Ps + (wave * 4 + j) * 512));
        }
#pragma unroll
        for (int j = 0; j < 2; ++j) {
            const int mv = (wave * 2 + j) * 8 + mrl;
            gload_lds16(V1t + ((size_t)bh * 64 + mv) * 1024 + s0 + cswz * 8,
                        (void*)(V1s + (wave * 2 + j) * 512));
            gload_lds16(V2t + ((size_t)bh * 64 + mv) * 1024 + s0 + cswz * 8,
                        (void*)(V2s + (wave * 2 + j) * 512));
        }
        __syncthreads();
#pragma unroll
        for (int sub = 0; sub < 2; ++sub) {
            short8 af[2], b1f[4], b2f_[4];
#pragma unroll
            for (int i = 0; i < 2; ++i) {
                const int ml = wave * 32 + i * 16 + ln;
                af[i] = *(const short8*)(Ps + ml * 64 + (((sub * 4 + lq) ^ (ml & 7)) * 8));
            }
#pragma unroll
            for (int j = 0; j < 4; ++j) {
                const int nl = j * 16 + ln;
                b1f[j] = *(const short8*)(V1s + nl * 64 + (((sub * 4 + lq) ^ (nl & 7)) * 8));
                b2f_[j] = *(const short8*)(V2s + nl * 64 + (((sub * 4 + lq) ^ (nl & 7)) * 8));
            }
#pragma unroll
            for (int i = 0; i < 2; ++i)
#pragma unroll
                for (int j = 0; j < 4; ++j) {
                    acc1[i][j] = __builtin_amdgcn_mfma_f32_16x16x32_bf16(af[i], b1f[j], acc1[i][j], 0, 0, 0);
                    acc2[i][j] = __builtin_amdgcn_mfma_f32_16x16x32_bf16(af[i], b2f_[j], acc2[i][j], 0, 0, 0);
                }
        }
    }

#pragma unroll
    for (int i = 0; i < 2; ++i) {
#pragma unroll
        for (int r = 0; r < 4; ++r) {
            const int l = l0 + wave * 32 + i * 16 + lq * 4 + r;
#pragma unroll
            for (int j = 0; j < 4; ++j) {
                const int d = j * 16 + ln;
                const size_t addr = ((size_t)l * 4 + bq) * 1024 + h * 64 + d;
                const float v = 0.5f * (acc1[i][j][r] * G1[addr] + acc2[i][j][r] * G2[addr]);
                tmpb[addr] = f2b(v);
            }
        }
    }
}

// ============================ launch ============================
extern "C" void kernel_launch(void* const* d_in, const int* in_sizes, int n_in,
                              void* d_out, int out_size, void* d_ws, size_t ws_size,
                              hipStream_t stream)
{
    const float* query = (const float*)d_in[0];
    const float* mod1  = (const float*)d_in[1];
    const float* mod2  = (const float*)d_in[2];
    const float* q_w  = (const float*)d_in[3];  const float* q_b  = (const float*)d_in[4];
    const float* k1_w = (const float*)d_in[5];  const float* k1_b = (const float*)d_in[6];
    const float* k2_w = (const float*)d_in[7];  const float* k2_b = (const float*)d_in[8];
    const float* v1_w = (const float*)d_in[9];  const float* v1_b = (const float*)d_in[10];
    const float* v2_w = (const float*)d_in[11]; const float* v2_b = (const float*)d_in[12];
    const float* g1_w = (const float*)d_in[13]; const float* g1_b = (const float*)d_in[14];
    const float* g2_w = (const float*)d_in[15]; const float* g2_b = (const float*)d_in[16];
    const float* o_w  = (const float*)d_in[17]; const float* o_b  = (const float*)d_in[18];
    float* out = (float*)d_out;

    const size_t MB = 1u << 20;
    char* w = (char*)d_ws;
    // base region (live across phases)
    ushort_t* Wqg  = (ushort_t*)(w + 0 * MB);    // 6 MB [q|g1|g2]^T
    ushort_t* Wkv1 = (ushort_t*)(w + 6 * MB);    // 4 MB [k1|v1]^T
    ushort_t* Wkv2 = (ushort_t*)(w + 10 * MB);   // 4 MB [k2|v2]^T
    ushort_t* Wo   = (ushort_t*)(w + 14 * MB);   // 2 MB
    ushort_t* Wk1l = (ushort_t*)(w + 16 * MB);   // 2 MB k1 lo
    ushort_t* Wk2l = (ushort_t*)(w + 18 * MB);   // 2 MB k2 lo
    ushort_t* qx   = (ushort_t*)(w + 20 * MB);   // 4 MB; dead after QG gemm
    ushort_t* tmpb = qx;                         // reuse for gated PV output
    ushort_t* m1h  = (ushort_t*)(w + 24 * MB);   // 8 MB; dead after KV1 gemm
    ushort_t* m2h  = (ushort_t*)(w + 32 * MB);   // 8 MB; dead after KV2 gemm
    float* G1 = (float*)(w + 24 * MB);           // overlays m1h (QG runs after KV)
    float* G2 = (float*)(w + 32 * MB);           // overlays m2h
    ushort_t* Qb  = (ushort_t*)(w + 40 * MB);    // 4 MB  (64*512*64*2 — full size!)
    ushort_t* K1b = (ushort_t*)(w + 44 * MB);    // 8 MB
    ushort_t* K2b = (ushort_t*)(w + 52 * MB);    // 8 MB
    ushort_t* V1t = (ushort_t*)(w + 60 * MB);    // 8 MB
    ushort_t* V2t = (ushort_t*)(w + 68 * MB);    // 8 MB
    float* ll = (float*)(w + 76 * MB);                    // 128 KB
    float* vv = (float*)(w + 76 * MB + 256 * 1024);       // 256 KB
    float* aa = (float*)(w + 76 * MB + 512 * 1024);
    float* va = (float*)(w + 76 * MB + 768 * 1024);
    // logits region 78..206 MB; transient overlays (all dead before scores):
    float* logits = (float*)(w + 78 * MB);       // 128 MB
    float* K1f = (float*)(w + 78 * MB);          // 16 MB fp32 K1 (for norms)
    float* K2f = (float*)(w + 94 * MB);          // 16 MB
    ushort_t* V1b = (ushort_t*)(w + 110 * MB);   // 8 MB
    ushort_t* V2b = (ushort_t*)(w + 118 * MB);   // 8 MB
    ushort_t* m1l = (ushort_t*)(w + 190 * MB);   // 8 MB mod1 lo
    ushort_t* m2l = (ushort_t*)(w + 198 * MB);   // 8 MB mod2 lo
    ushort_t* attn = (ushort_t*)logits;          // bf16, row stride 2048 elems

    // casts
    cast_q_kernel<<<1024, 256, 0, stream>>>(query, qx);
    cast_mod_kernel<<<dim3(2048, 2), 256, 0, stream>>>(mod1, mod2, m1h, m1l, m2h, m2l);
    WArgs wa;
    const float* srcs[8] = {q_w, g1_w, g2_w, k1_w, v1_w, k2_w, v2_w, o_w};
    ushort_t* his[8] = {Wqg, Wqg + (size_t)1024 * 1024, Wqg + (size_t)2048 * 1024,
                        Wkv1, Wkv1 + (size_t)1024 * 1024, Wkv2, Wkv2 + (size_t)1024 * 1024, Wo};
    ushort_t* los[8] = {nullptr, nullptr, nullptr, Wk1l, nullptr, Wk2l, nullptr, nullptr};
    for (int i = 0; i < 8; ++i) { wa.src[i] = srcs[i]; wa.hi[i] = his[i]; wa.lo[i] = los[i]; }
    wcast_kernel<<<dim3(16, 16, 8), 256, 0, stream>>>(wa);

    // projections: KV (K split-precision fp32 out, V bf16), then QG
    gemm_mfma<5><<<dim3(16, 32), 256, 0, stream>>>(m1h, m1l, Wkv1, Wk1l, k1_b, v1_b, nullptr,
                                                   K1f, V1b, nullptr, 1.f);
    gemm_mfma<5><<<dim3(16, 32), 256, 0, stream>>>(m2h, m2l, Wkv2, Wk2l, k2_b, v2_b, nullptr,
                                                   K2f, V2b, nullptr, 1.f);
    gemm_mfma<4><<<dim3(24, 16), 256, 0, stream>>>(qx, nullptr, Wqg, nullptr, q_b, g1_b, g2_b,
                                                   Qb, G1, G2, 0.125f);

    // norms (fp32 K) + K cast + V transpose
    norms_cast_k_kernel<<<16384, 256, 0, stream>>>(K1f, K2f, K1b, K2b, vv, aa, va);
    normsq_kernel<<<8192, 256, 0, stream>>>(Qb, ll);
    vtrans_kernel<<<dim3(16, 64, 2), 256, 0, stream>>>(V1b, V2b, V1t, V2t);

    // attention
    scores_kernel<<<dim3(8, 4, 64), 256, 0, stream>>>(Qb, K1b, K2b, ll, vv, aa, va, logits);
    softmax_avg_kernel<<<2048, 256, 0, stream>>>(logits, out + (size_t)LQ * NB * EDIM);
    pv_gate_kernel<<<dim3(4, 64), 256, 0, stream>>>(attn, V1t, V2t, G1, G2, tmpb);

    // output projection
    gemm_mfma<0><<<dim3(8, 16), 256, 0, stream>>>(tmpb, nullptr, Wo, nullptr, o_b, nullptr, nullptr,
                                                  out, nullptr, nullptr, 1.f);
}

// Round 6
// 397.363 us; speedup vs baseline: 3.4978x; 1.0974x over previous
//
#include <hip/hip_runtime.h>
#include <cstddef>
#include <cstdint>

typedef unsigned short ushort_t;
typedef unsigned int uint_t;
typedef __attribute__((ext_vector_type(8))) short short8;
typedef __attribute__((ext_vector_type(4))) float f32x4;

#define EDIM 1024
#define NHEAD 16
#define HDIM 64
#define NB 4
#define LQ 512
#define SK 1024
#define BHD 64

__device__ __forceinline__ ushort_t f2b(float f) {
    uint_t u = __float_as_uint(f);
    return (ushort_t)((u + 0x7fffu + ((u >> 16) & 1u)) >> 16);
}
__device__ __forceinline__ float b2f(ushort_t b) {
    return __uint_as_float(((uint_t)b) << 16);
}

__device__ __forceinline__ void gload_lds16(const void* g, void* l) {
    __builtin_amdgcn_global_load_lds((const __attribute__((address_space(1))) void*)g,
                                     (__attribute__((address_space(3))) void*)l, 16, 0, 0);
}

// ============ mega projection GEMM: all 5 jobs in one balanced launch ======
// blocks 0..255:    K1 (3-pass split precision) -> K1f fp32 head-split
// blocks 256..511:  K2 (3-pass)                 -> K2f fp32 head-split
// blocks 512..767:  V1 (1-pass)                 -> V1b bf16 head-split
// blocks 768..1023: V2 (1-pass)                 -> V2b bf16 head-split
// blocks 1024..1407: QG (1-pass): q -> Qb bf16 head-split *0.125;
//                    g1/g2 -> G1b/G2b bf16 sigmoid flat
struct MegaArgs {
    const ushort_t *qx, *m1h, *m1l, *m2h, *m2l;
    const ushort_t *Wqg, *Wkv1, *Wkv2, *Wk1l, *Wk2l;
    const float *q_b, *k1_b, *k2_b, *v1_b, *v2_b, *g1_b, *g2_b;
    float *K1f, *K2f;
    ushort_t *V1b, *V2b, *Qb, *G1b, *G2b;
};

__global__ __launch_bounds__(256, 2)
void mega_gemm(MegaArgs a)
{
    __shared__ ushort_t As[128 * 64];
    __shared__ ushort_t Bs[128 * 64];
    const int tid = threadIdx.x;
    const int wave = tid >> 6, lane = tid & 63;
    const int ln = lane & 15, lq = lane >> 4;
    const int wm = wave & 1, wn = wave >> 1;
    const int cswz = (lane & 7) ^ ((lane >> 3) & 7);
    const int mrl = lane >> 3;

    const int id = blockIdx.x;
    const ushort_t *A, *Al, *B, *Bl;
    const float* bias;
    int npass, row0, col0, kind;
    if (id < 512) {  // K split-precision, long blocks first
        kind = id >> 8;
        const int t = id & 255;
        col0 = (t & 7) * 128; row0 = (t >> 3) * 128; npass = 3;
        A = kind ? a.m2h : a.m1h;  Al = kind ? a.m2l : a.m1l;
        B = kind ? a.Wkv2 : a.Wkv1; Bl = kind ? a.Wk2l : a.Wk1l;
        bias = kind ? a.k2_b : a.k1_b;
    } else if (id < 1024) {  // V
        int t = id - 512; kind = 2 + (t >> 8); t &= 255;
        col0 = (t & 7) * 128; row0 = (t >> 3) * 128; npass = 1;
        A = (kind == 2) ? a.m1h : a.m2h; Al = A;
        B = ((kind == 2) ? a.Wkv1 : a.Wkv2) + (size_t)1024 * 1024; Bl = B;
        bias = (kind == 2) ? a.v1_b : a.v2_b;
    } else {  // QG
        const int t = id - 1024; kind = 4;
        const int c = t % 24, rr = t / 24;
        col0 = c * 128; row0 = rr * 128; npass = 1;
        A = a.qx; Al = A; B = a.Wqg; Bl = B;
        const int seg = c >> 3;
        bias = (seg == 0) ? a.q_b : ((seg == 1) ? a.g1_b : a.g2_b);
    }

    f32x4 zero = {0.f, 0.f, 0.f, 0.f};
    f32x4 acc[4][4];
#pragma unroll
    for (int i = 0; i < 4; ++i)
#pragma unroll
        for (int j = 0; j < 4; ++j) acc[i][j] = zero;

    for (int pp = 0; pp < npass; ++pp) {
        const ushort_t* Ab = (pp == 2) ? Al : A;   // AhBh + AhBl + AlBh
        const ushort_t* Bb = (pp == 1) ? Bl : B;
        for (int kk = 0; kk < 1024; kk += 64) {
            __syncthreads();
#pragma unroll
            for (int j = 0; j < 4; ++j) {
                const int mr = (wave * 4 + j) * 8 + mrl;
                gload_lds16(Ab + (size_t)(row0 + mr) * 1024 + kk + cswz * 8,
                            (void*)(As + (wave * 4 + j) * 512));
                gload_lds16(Bb + (size_t)(col0 + mr) * 1024 + kk + cswz * 8,
                            (void*)(Bs + (wave * 4 + j) * 512));
            }
            __syncthreads();
#pragma unroll
            for (int sub = 0; sub < 2; ++sub) {
                short8 af[4], bfv[4];
#pragma unroll
                for (int i = 0; i < 4; ++i) {
                    const int ml = wm * 64 + i * 16 + ln;
                    af[i] = *(const short8*)(As + ml * 64 + (((sub * 4 + lq) ^ (ml & 7)) * 8));
                    const int nl = wn * 64 + i * 16 + ln;
                    bfv[i] = *(const short8*)(Bs + nl * 64 + (((sub * 4 + lq) ^ (nl & 7)) * 8));
                }
#pragma unroll
                for (int i = 0; i < 4; ++i)
#pragma unroll
                    for (int j = 0; j < 4; ++j)
                        acc[i][j] = __builtin_amdgcn_mfma_f32_16x16x32_bf16(af[i], bfv[j], acc[i][j], 0, 0, 0);
            }
        }
    }

#pragma unroll
    for (int i = 0; i < 4; ++i) {
#pragma unroll
        for (int r = 0; r < 4; ++r) {
            const int row = row0 + wm * 64 + i * 16 + lq * 4 + r;
#pragma unroll
            for (int j = 0; j < 4; ++j) {
                const int col = col0 + wn * 64 + j * 16 + ln;
                const int lc = col & 1023;
                float v = acc[i][j][r] + bias[lc];
                if (kind <= 1) {            // K fp32 head-split (S=1024)
                    const int s = row >> 2, b = row & 3, h = lc >> 6, d = lc & 63;
                    float* Y = kind ? a.K2f : a.K1f;
                    Y[(((size_t)(b * 16 + h)) * 1024 + s) * 64 + d] = v;
                } else if (kind <= 3) {     // V bf16 head-split
                    const int s = row >> 2, b = row & 3, h = lc >> 6, d = lc & 63;
                    ushort_t* Y = (kind == 2) ? a.V1b : a.V2b;
                    Y[(((size_t)(b * 16 + h)) * 1024 + s) * 64 + d] = f2b(v);
                } else {
                    const int seg = col >> 10;
                    if (seg == 0) {         // Q bf16 head-split (L=512), *scale
                        v *= 0.125f;
                        const int s = row >> 2, b = row & 3, h = lc >> 6, d = lc & 63;
                        a.Qb[(((size_t)(b * 16 + h)) * 512 + s) * 64 + d] = f2b(v);
                    } else {                // gates bf16 sigmoid flat
                        v = 1.0f / (1.0f + __expf(-v));
                        ushort_t* Y = (seg == 1) ? a.G1b : a.G2b;
                        Y[(size_t)row * 1024 + lc] = f2b(v);
                    }
                }
            }
        }
    }
}

// =============== fused input/weight casts (one launch) ===============
struct CastArgs {
    const float* q; const float* m1; const float* m2;
    ushort_t* qx; ushort_t* m1h; ushort_t* m1l; ushort_t* m2h; ushort_t* m2l;
    const float* wsrc[8];
    ushort_t* whi[8];
    ushort_t* wlo[8];
};

__global__ __launch_bounds__(256)
void casts_kernel(CastArgs a)
{
    __shared__ float T[64][65];
    const int id = blockIdx.x;
    const int tid = threadIdx.x;
    if (id < 1024) {                       // query cast
        const size_t i = ((size_t)id * 256 + tid) * 8;
        float4 x = *(const float4*)(a.q + i);
        float4 y = *(const float4*)(a.q + i + 4);
        ushort_t o[8] = {f2b(x.x), f2b(x.y), f2b(x.z), f2b(x.w), f2b(y.x), f2b(y.y), f2b(y.z), f2b(y.w)};
        *(uint4*)( (void*)(a.qx + i) ) = *(const uint4*)o;
    } else if (id < 5120) {                // mod hi/lo split casts
        const int t = id - 1024;
        const int which = t >> 11;
        const float* x = which ? a.m2 : a.m1;
        ushort_t* yh = which ? a.m2h : a.m1h;
        ushort_t* yl = which ? a.m2l : a.m1l;
        const size_t i = ((size_t)(t & 2047) * 256 + tid) * 8;
        float v[8];
        *(float4*)v = *(const float4*)(x + i);
        *(float4*)(v + 4) = *(const float4*)(x + i + 4);
        ushort_t oh[8], ol[8];
#pragma unroll
        for (int k = 0; k < 8; ++k) {
            oh[k] = f2b(v[k]);
            ol[k] = f2b(v[k] - b2f(oh[k]));
        }
        *(uint4*)( (void*)(yh + i) ) = *(const uint4*)oh;
        *(uint4*)( (void*)(yl + i) ) = *(const uint4*)ol;
    } else {                               // weight transpose+cast
        const int t = id - 5120;
        const int z = t >> 8, x = t & 15, y = (t >> 4) & 15;
        const float* W = a.wsrc[z];
        ushort_t* Th = a.whi[z];
        ushort_t* Tl = a.wlo[z];
        const int k0 = x * 64, n0 = y * 64;
        const int r = tid >> 2, cg = (tid & 3) * 16;
#pragma unroll
        for (int u = 0; u < 4; ++u) {
            float4 v = *(const float4*)(W + (size_t)(k0 + r) * 1024 + n0 + cg + u * 4);
            T[r][cg + u * 4 + 0] = v.x; T[r][cg + u * 4 + 1] = v.y;
            T[r][cg + u * 4 + 2] = v.z; T[r][cg + u * 4 + 3] = v.w;
        }
        __syncthreads();
        ushort_t oh[16], ol[16];
#pragma unroll
        for (int u = 0; u < 16; ++u) {
            float v = T[cg + u][r];
            oh[u] = f2b(v);
            ol[u] = f2b(v - b2f(oh[u]));
        }
        ushort_t* dh = Th + (size_t)(n0 + r) * 1024 + k0 + cg;
        *(uint4*)( (void*)dh ) = *(const uint4*)oh;
        *(uint4*)( (void*)(dh + 8) ) = *(const uint4*)(oh + 8);
        if (Tl) {
            ushort_t* dl = Tl + (size_t)(n0 + r) * 1024 + k0 + cg;
            *(uint4*)( (void*)dl ) = *(const uint4*)ol;
            *(uint4*)( (void*)(dl + 8) ) = *(const uint4*)(ol + 8);
        }
    }
}

// ====== fused prep: K norms+cast, Q norms, V transpose (one launch) ======
__global__ __launch_bounds__(256)
void prep_kernel(const float* __restrict__ K1f, const float* __restrict__ K2f,
                 ushort_t* __restrict__ K1b, ushort_t* __restrict__ K2b,
                 float* __restrict__ vv, float* __restrict__ aa, float* __restrict__ va,
                 const ushort_t* __restrict__ Qb, float* __restrict__ ll,
                 const ushort_t* __restrict__ V1b, const ushort_t* __restrict__ V2b,
                 ushort_t* __restrict__ V1t, ushort_t* __restrict__ V2t)
{
    __shared__ float T[64][65];
    const int id = blockIdx.x;
    const int tid = threadIdx.x;
    const int wave = tid >> 6, lane = tid & 63;
    if (id < 16384) {                      // K norms (fp32) + bf16 cast
        const int row = id * 4 + wave;
        const float x1 = K1f[(size_t)row * 64 + lane];
        const float x2 = K2f[(size_t)row * 64 + lane];
        K1b[(size_t)row * 64 + lane] = f2b(x1);
        K2b[(size_t)row * 64 + lane] = f2b(x2);
        float s1 = x1 * x1, s2 = x2 * x2, s3 = x1 * x2;
#pragma unroll
        for (int o = 1; o < 64; o <<= 1) {
            s1 += __shfl_xor(s1, o);
            s2 += __shfl_xor(s2, o);
            s3 += __shfl_xor(s3, o);
        }
        if (lane == 0) { vv[row] = s1; aa[row] = s2; va[row] = s3; }
    } else if (id < 24576) {               // Q norms
        const int row = (id - 16384) * 4 + wave;
        const float x = b2f(Qb[(size_t)row * 64 + lane]);
        float s = x * x;
#pragma unroll
        for (int o = 1; o < 64; o <<= 1) s += __shfl_xor(s, o);
        if (lane == 0) ll[row] = s;
    } else {                               // V transpose
        const int t = id - 24576;
        const int z = t >> 10, bh = (t >> 4) & 63, s0 = (t & 15) * 64;
        const ushort_t* S = z ? V2b : V1b;
        ushort_t* D = z ? V2t : V1t;
        const int r = tid >> 2, cg = (tid & 3) * 16;
        ushort_t buf[16];
        const ushort_t* sp = S + ((size_t)bh * 1024 + s0 + r) * 64 + cg;
        *(uint4*)buf = *(const uint4*)sp;
        *(uint4*)(buf + 8) = *(const uint4*)(sp + 8);
#pragma unroll
        for (int u = 0; u < 16; ++u) T[r][cg + u] = b2f(buf[u]);
        __syncthreads();
        ushort_t o[16];
#pragma unroll
        for (int u = 0; u < 16; ++u) o[u] = f2b(T[cg + u][r]);
        ushort_t* d = D + ((size_t)bh * 64 + r) * 1024 + s0 + cg;
        *(uint4*)( (void*)d ) = *(const uint4*)o;
        *(uint4*)( (void*)(d + 8) ) = *(const uint4*)(o + 8);
    }
}

// =================== scores: logits = lv + la - 1.5*sqrt(det) =============
__global__ __launch_bounds__(256, 2)
void scores_kernel(const ushort_t* __restrict__ Qb, const ushort_t* __restrict__ K1b,
                   const ushort_t* __restrict__ K2b, const float* __restrict__ ll,
                   const float* __restrict__ vv, const float* __restrict__ aa,
                   const float* __restrict__ va, float* __restrict__ logits)
{
    __shared__ ushort_t Qs[128 * 64];
    __shared__ ushort_t K1s[128 * 64];
    __shared__ ushort_t K2s[128 * 64];
    __shared__ float llS[128], vvS[128], aaS[128], vaS[128];
    const int tid = threadIdx.x;
    const int wave = tid >> 6, lane = tid & 63;
    const int ln = lane & 15, lq = lane >> 4;
    const int wm = wave & 1, wn = wave >> 1;
    const int bh = blockIdx.z;
    const int l0 = blockIdx.y * 128, s0 = blockIdx.x * 128;
    const int cswz = (lane & 7) ^ ((lane >> 3) & 7);
    const int mrl = lane >> 3;

    if (tid < 128) {
        llS[tid] = ll[(size_t)bh * 512 + l0 + tid];
        vvS[tid] = vv[(size_t)bh * 1024 + s0 + tid];
        aaS[tid] = aa[(size_t)bh * 1024 + s0 + tid];
        vaS[tid] = va[(size_t)bh * 1024 + s0 + tid];
    }
#pragma unroll
    for (int j = 0; j < 4; ++j) {
        const int mr = (wave * 4 + j) * 8 + mrl;
        gload_lds16(Qb + ((size_t)bh * 512 + l0 + mr) * 64 + cswz * 8, (void*)(Qs + (wave * 4 + j) * 512));
        gload_lds16(K1b + ((size_t)bh * 1024 + s0 + mr) * 64 + cswz * 8, (void*)(K1s + (wave * 4 + j) * 512));
        gload_lds16(K2b + ((size_t)bh * 1024 + s0 + mr) * 64 + cswz * 8, (void*)(K2s + (wave * 4 + j) * 512));
    }
    __syncthreads();

    f32x4 zero = {0.f, 0.f, 0.f, 0.f};
    f32x4 lv[4][4], la[4][4];
#pragma unroll
    for (int i = 0; i < 4; ++i)
#pragma unroll
        for (int j = 0; j < 4; ++j) { lv[i][j] = zero; la[i][j] = zero; }

#pragma unroll
    for (int sub = 0; sub < 2; ++sub) {
        short8 qf[4], k1f[4], k2f[4];
#pragma unroll
        for (int i = 0; i < 4; ++i) {
            const int ml = wm * 64 + i * 16 + ln;
            qf[i] = *(const short8*)(Qs + ml * 64 + (((sub * 4 + lq) ^ (ml & 7)) * 8));
            const int nl = wn * 64 + i * 16 + ln;
            k1f[i] = *(const short8*)(K1s + nl * 64 + (((sub * 4 + lq) ^ (nl & 7)) * 8));
            k2f[i] = *(const short8*)(K2s + nl * 64 + (((sub * 4 + lq) ^ (nl & 7)) * 8));
        }
#pragma unroll
        for (int i = 0; i < 4; ++i)
#pragma unroll
            for (int j = 0; j < 4; ++j) {
                lv[i][j] = __builtin_amdgcn_mfma_f32_16x16x32_bf16(qf[i], k1f[j], lv[i][j], 0, 0, 0);
                la[i][j] = __builtin_amdgcn_mfma_f32_16x16x32_bf16(qf[i], k2f[j], la[i][j], 0, 0, 0);
            }
    }

#pragma unroll
    for (int i = 0; i < 4; ++i) {
#pragma unroll
        for (int r = 0; r < 4; ++r) {
            const int l_loc = wm * 64 + i * 16 + lq * 4 + r;
            const float LL = llS[l_loc];
#pragma unroll
            for (int j = 0; j < 4; ++j) {
                const int s_loc = wn * 64 + j * 16 + ln;
                const float VV = vvS[s_loc], AA = aaS[s_loc], VA = vaS[s_loc];
                const float LV = lv[i][j][r], LA = la[i][j][r];
                float det = LL * (VV * AA - VA * VA) - LV * (LV * AA - LA * VA) + LA * (LV * VA - LA * VV);
                det = fmaxf(det, 1e-8f);
                logits[((size_t)bh * 512 + l0 + l_loc) * 1024 + s0 + s_loc] = LV + LA - 1.5f * sqrtf(det);
            }
        }
    }
}

// ======= softmax (fp32 -> bf16 in place) fused with head-average ==========
__global__ __launch_bounds__(256)
void softmax_avg_kernel(float* __restrict__ logits, float* __restrict__ avg)
{
    __shared__ float part[4][1024];
    const int b = blockIdx.x >> 9, l = blockIdx.x & 511;
    const int wave = threadIdx.x >> 6, lane = threadIdx.x & 63;
    float pacc[16];
#pragma unroll
    for (int u = 0; u < 16; ++u) pacc[u] = 0.f;
#pragma unroll
    for (int jj = 0; jj < 4; ++jj) {
        const int h = wave * 4 + jj;
        float* rowp = logits + (((size_t)(b * 16 + h)) * 512 + l) * 1024;
        float4 v[4];
#pragma unroll
        for (int c = 0; c < 4; ++c) v[c] = *(const float4*)(rowp + c * 256 + lane * 4);
        float m = -3.4e38f;
#pragma unroll
        for (int c = 0; c < 4; ++c) m = fmaxf(m, fmaxf(fmaxf(v[c].x, v[c].y), fmaxf(v[c].z, v[c].w)));
#pragma unroll
        for (int o = 1; o < 64; o <<= 1) m = fmaxf(m, __shfl_xor(m, o));
        float s = 0.f;
#pragma unroll
        for (int c = 0; c < 4; ++c) {
            v[c].x = __expf(v[c].x - m); v[c].y = __expf(v[c].y - m);
            v[c].z = __expf(v[c].z - m); v[c].w = __expf(v[c].w - m);
            s += v[c].x + v[c].y + v[c].z + v[c].w;
        }
#pragma unroll
        for (int o = 1; o < 64; o <<= 1) s += __shfl_xor(s, o);
        const float inv = 1.0f / s;
        ushort_t* arow = (ushort_t*)rowp;
#pragma unroll
        for (int c = 0; c < 4; ++c) {
            const float p0 = v[c].x * inv, p1 = v[c].y * inv, p2 = v[c].z * inv, p3 = v[c].w * inv;
            ushort_t w[4] = {f2b(p0), f2b(p1), f2b(p2), f2b(p3)};
            *(uint2*)( (void*)(arow + c * 256 + lane * 4) ) = *(const uint2*)w;
            pacc[c * 4 + 0] += p0; pacc[c * 4 + 1] += p1;
            pacc[c * 4 + 2] += p2; pacc[c * 4 + 3] += p3;
        }
    }
#pragma unroll
    for (int c = 0; c < 4; ++c) {
        float4 pv = {pacc[c * 4 + 0], pacc[c * 4 + 1], pacc[c * 4 + 2], pacc[c * 4 + 3]};
        *(float4*)(&part[wave][c * 256 + lane * 4]) = pv;
    }
    __syncthreads();
    const int s0 = threadIdx.x * 4;
    float4 a0 = *(const float4*)(&part[0][s0]);
    float4 a1 = *(const float4*)(&part[1][s0]);
    float4 a2 = *(const float4*)(&part[2][s0]);
    float4 a3 = *(const float4*)(&part[3][s0]);
    float4 o;
    o.x = (a0.x + a1.x + a2.x + a3.x) * 0.0625f;
    o.y = (a0.y + a1.y + a2.y + a3.y) * 0.0625f;
    o.z = (a0.z + a1.z + a2.z + a3.z) * 0.0625f;
    o.w = (a0.w + a1.w + a2.w + a3.w) * 0.0625f;
    *(float4*)(avg + ((size_t)(b * 512 + l)) * 1024 + s0) = o;
}

// =================== PV (v1,v2) + gating -> tmp bf16 [t][E] ================
__global__ __launch_bounds__(256, 2)
void pv_gate_kernel(const ushort_t* __restrict__ attn, const ushort_t* __restrict__ V1t,
                    const ushort_t* __restrict__ V2t, const ushort_t* __restrict__ G1,
                    const ushort_t* __restrict__ G2, ushort_t* __restrict__ tmpb)
{
    __shared__ ushort_t Ps[128 * 64];
    __shared__ ushort_t V1s[64 * 64];
    __shared__ ushort_t V2s[64 * 64];
    const int tid = threadIdx.x;
    const int wave = tid >> 6, lane = tid & 63;
    const int ln = lane & 15, lq = lane >> 4;
    const int bh = blockIdx.y;
    const int l0 = blockIdx.x * 128;
    const int cswz = (lane & 7) ^ ((lane >> 3) & 7);
    const int mrl = lane >> 3;
    const int bq = bh >> 4, h = bh & 15;

    f32x4 zero = {0.f, 0.f, 0.f, 0.f};
    f32x4 acc1[2][4], acc2[2][4];
#pragma unroll
    for (int i = 0; i < 2; ++i)
#pragma unroll
        for (int j = 0; j < 4; ++j) { acc1[i][j] = zero; acc2[i][j] = zero; }

    for (int s0 = 0; s0 < 1024; s0 += 64) {
        __syncthreads();
#pragma unroll
        for (int j = 0; j < 4; ++j) {
            const int mr = (wave * 4 + j) * 8 + mrl;
            gload_lds16(attn + ((size_t)bh * 512 + l0 + mr) * 2048 + s0 + cswz * 8,
                        (void*)(Ps + (wave * 4 + j) * 512));
        }
#pragma unroll
        for (int j = 0; j < 2; ++j) {
            const int mv = (wave * 2 + j) * 8 + mrl;
            gload_lds16(V1t + ((size_t)bh * 64 + mv) * 1024 + s0 + cswz * 8,
                        (void*)(V1s + (wave * 2 + j) * 512));
            gload_lds16(V2t + ((size_t)bh * 64 + mv) * 1024 + s0 + cswz * 8,
                        (void*)(V2s + (wave * 2 + j) * 512));
        }
        __syncthreads();
#pragma unroll
        for (int sub = 0; sub < 2; ++sub) {
            short8 af[2], b1f[4], b2f_[4];
#pragma unroll
            for (int i = 0; i < 2; ++i) {
                const int ml = wave * 32 + i * 16 + ln;
                af[i] = *(const short8*)(Ps + ml * 64 + (((sub * 4 + lq) ^ (ml & 7)) * 8));
            }
#pragma unroll
            for (int j = 0; j < 4; ++j) {
                const int nl = j * 16 + ln;
                b1f[j] = *(const short8*)(V1s + nl * 64 + (((sub * 4 + lq) ^ (nl & 7)) * 8));
                b2f_[j] = *(const short8*)(V2s + nl * 64 + (((sub * 4 + lq) ^ (nl & 7)) * 8));
            }
#pragma unroll
            for (int i = 0; i < 2; ++i)
#pragma unroll
                for (int j = 0; j < 4; ++j) {
                    acc1[i][j] = __builtin_amdgcn_mfma_f32_16x16x32_bf16(af[i], b1f[j], acc1[i][j], 0, 0, 0);
                    acc2[i][j] = __builtin_amdgcn_mfma_f32_16x16x32_bf16(af[i], b2f_[j], acc2[i][j], 0, 0, 0);
                }
        }
    }

#pragma unroll
    for (int i = 0; i < 2; ++i) {
#pragma unroll
        for (int r = 0; r < 4; ++r) {
            const int l = l0 + wave * 32 + i * 16 + lq * 4 + r;
#pragma unroll
            for (int j = 0; j < 4; ++j) {
                const int d = j * 16 + ln;
                const size_t addr = ((size_t)l * 4 + bq) * 1024 + h * 64 + d;
                const float v = 0.5f * (acc1[i][j][r] * b2f(G1[addr]) + acc2[i][j][r] * b2f(G2[addr]));
                tmpb[addr] = f2b(v);
            }
        }
    }
}

// ============ o-proj: 64x128 tiles, 256 blocks (fixed coverage) ============
// per wave: 32 rows (wm) x 64 cols (wn); A staged 64 rows, B staged 128 rows
__global__ __launch_bounds__(256, 2)
void gemm_o64(const ushort_t* __restrict__ A, const ushort_t* __restrict__ B,
              const float* __restrict__ bias, float* __restrict__ Y)
{
    __shared__ ushort_t As[64 * 64];
    __shared__ ushort_t Bs[128 * 64];
    const int tid = threadIdx.x;
    const int wave = tid >> 6, lane = tid & 63;
    const int ln = lane & 15, lq = lane >> 4;
    const int row0 = blockIdx.y * 64, col0 = blockIdx.x * 128;
    const int wm = wave & 1, wn = wave >> 1;
    const int cswz = (lane & 7) ^ ((lane >> 3) & 7);
    const int mrl = lane >> 3;

    f32x4 zero = {0.f, 0.f, 0.f, 0.f};
    f32x4 acc[2][4];
#pragma unroll
    for (int i = 0; i < 2; ++i)
#pragma unroll
        for (int j = 0; j < 4; ++j) acc[i][j] = zero;

    for (int kk = 0; kk < 1024; kk += 64) {
        __syncthreads();
#pragma unroll
        for (int j = 0; j < 2; ++j) {       // A: 64 rows
            const int mr = (wave * 2 + j) * 8 + mrl;
            gload_lds16(A + (size_t)(row0 + mr) * 1024 + kk + cswz * 8,
                        (void*)(As + (wave * 2 + j) * 512));
        }
#pragma unroll
        for (int j = 0; j < 4; ++j) {       // B: 128 rows
            const int mr = (wave * 4 + j) * 8 + mrl;
            gload_lds16(B + (size_t)(col0 + mr) * 1024 + kk + cswz * 8,
                        (void*)(Bs + (wave * 4 + j) * 512));
        }
        __syncthreads();
#pragma unroll
        for (int sub = 0; sub < 2; ++sub) {
            short8 af[2], bfv[4];
#pragma unroll
            for (int i = 0; i < 2; ++i) {
                const int ml = wm * 32 + i * 16 + ln;
                af[i] = *(const short8*)(As + ml * 64 + (((sub * 4 + lq) ^ (ml & 7)) * 8));
            }
#pragma unroll
            for (int j = 0; j < 4; ++j) {
                const int nl = wn * 64 + j * 16 + ln;
                bfv[j] = *(const short8*)(Bs + nl * 64 + (((sub * 4 + lq) ^ (nl & 7)) * 8));
            }
#pragma unroll
            for (int i = 0; i < 2; ++i)
#pragma unroll
                for (int j = 0; j < 4; ++j)
                    acc[i][j] = __builtin_amdgcn_mfma_f32_16x16x32_bf16(af[i], bfv[j], acc[i][j], 0, 0, 0);
        }
    }

#pragma unroll
    for (int i = 0; i < 2; ++i) {
#pragma unroll
        for (int r = 0; r < 4; ++r) {
            const int row = row0 + wm * 32 + i * 16 + lq * 4 + r;
#pragma unroll
            for (int j = 0; j < 4; ++j) {
                const int col = col0 + wn * 64 + j * 16 + ln;
                Y[(size_t)row * 1024 + col] = acc[i][j][r] + bias[col];
            }
        }
    }
}

// ============================ launch ============================
extern "C" void kernel_launch(void* const* d_in, const int* in_sizes, int n_in,
                              void* d_out, int out_size, void* d_ws, size_t ws_size,
                              hipStream_t stream)
{
    const float* query = (const float*)d_in[0];
    const float* mod1  = (const float*)d_in[1];
    const float* mod2  = (const float*)d_in[2];
    const float* q_w  = (const float*)d_in[3];  const float* q_b  = (const float*)d_in[4];
    const float* k1_w = (const float*)d_in[5];  const float* k1_b = (const float*)d_in[6];
    const float* k2_w = (const float*)d_in[7];  const float* k2_b = (const float*)d_in[8];
    const float* v1_w = (const float*)d_in[9];  const float* v1_b = (const float*)d_in[10];
    const float* v2_w = (const float*)d_in[11]; const float* v2_b = (const float*)d_in[12];
    const float* g1_w = (const float*)d_in[13]; const float* g1_b = (const float*)d_in[14];
    const float* g2_w = (const float*)d_in[15]; const float* g2_b = (const float*)d_in[16];
    const float* o_w  = (const float*)d_in[17]; const float* o_b  = (const float*)d_in[18];
    float* out = (float*)d_out;

    const size_t MB = 1u << 20;
    char* w = (char*)d_ws;
    // persistent region (0..78 MB)
    ushort_t* Wqg  = (ushort_t*)(w + 0 * MB);    // 6 MB [q|g1|g2]^T
    ushort_t* Wkv1 = (ushort_t*)(w + 6 * MB);    // 4 MB [k1|v1]^T
    ushort_t* Wkv2 = (ushort_t*)(w + 10 * MB);   // 4 MB [k2|v2]^T
    ushort_t* Wo   = (ushort_t*)(w + 14 * MB);   // 2 MB
    ushort_t* Wk1l = (ushort_t*)(w + 16 * MB);   // 2 MB
    ushort_t* Wk2l = (ushort_t*)(w + 18 * MB);   // 2 MB
    ushort_t* qx   = (ushort_t*)(w + 20 * MB);   // 4 MB; dead after mega-GEMM
    ushort_t* tmpb = qx;                         // reuse for gated PV output
    ushort_t* Qb   = (ushort_t*)(w + 24 * MB);   // 4 MB (full 64*512*64)
    ushort_t* K1b  = (ushort_t*)(w + 28 * MB);   // 8 MB
    ushort_t* K2b  = (ushort_t*)(w + 36 * MB);   // 8 MB
    ushort_t* V1t  = (ushort_t*)(w + 44 * MB);   // 8 MB
    ushort_t* V2t  = (ushort_t*)(w + 52 * MB);   // 8 MB
    ushort_t* G1b  = (ushort_t*)(w + 60 * MB);   // 4 MB bf16 gates
    ushort_t* G2b  = (ushort_t*)(w + 64 * MB);   // 4 MB
    float* ll = (float*)(w + 68 * MB);                   // 128 KB
    float* vv = (float*)(w + 68 * MB + 256 * 1024);      // 256 KB
    float* aa = (float*)(w + 68 * MB + 512 * 1024);
    float* va = (float*)(w + 68 * MB + 768 * 1024);
    // logits region 78..206 MB; transient overlays all dead before scores:
    float* logits = (float*)(w + 78 * MB);       // 128 MB
    ushort_t* m1h = (ushort_t*)(w + 78 * MB);    // 8 MB  (dead after mega-GEMM)
    ushort_t* m2h = (ushort_t*)(w + 86 * MB);    // 8 MB
    ushort_t* m1l = (ushort_t*)(w + 94 * MB);    // 8 MB
    ushort_t* m2l = (ushort_t*)(w + 102 * MB);   // 8 MB
    float* K1f = (float*)(w + 110 * MB);         // 16 MB (dead after prep)
    float* K2f = (float*)(w + 126 * MB);         // 16 MB
    ushort_t* V1b = (ushort_t*)(w + 142 * MB);   // 8 MB (dead after prep)
    ushort_t* V2b = (ushort_t*)(w + 150 * MB);   // 8 MB
    ushort_t* attn = (ushort_t*)logits;          // bf16, row stride 2048 elems

    // 1) fused casts
    CastArgs ca;
    ca.q = query; ca.m1 = mod1; ca.m2 = mod2;
    ca.qx = qx; ca.m1h = m1h; ca.m1l = m1l; ca.m2h = m2h; ca.m2l = m2l;
    const float* srcs[8] = {q_w, g1_w, g2_w, k1_w, v1_w, k2_w, v2_w, o_w};
    ushort_t* his[8] = {Wqg, Wqg + (size_t)1024 * 1024, Wqg + (size_t)2048 * 1024,
                        Wkv1, Wkv1 + (size_t)1024 * 1024, Wkv2, Wkv2 + (size_t)1024 * 1024, Wo};
    ushort_t* los[8] = {nullptr, nullptr, nullptr, Wk1l, nullptr, Wk2l, nullptr, nullptr};
    for (int i = 0; i < 8; ++i) { ca.wsrc[i] = srcs[i]; ca.whi[i] = his[i]; ca.wlo[i] = los[i]; }
    casts_kernel<<<7168, 256, 0, stream>>>(ca);

    // 2) all projections, one balanced launch
    MegaArgs ma;
    ma.qx = qx; ma.m1h = m1h; ma.m1l = m1l; ma.m2h = m2h; ma.m2l = m2l;
    ma.Wqg = Wqg; ma.Wkv1 = Wkv1; ma.Wkv2 = Wkv2; ma.Wk1l = Wk1l; ma.Wk2l = Wk2l;
    ma.q_b = q_b; ma.k1_b = k1_b; ma.k2_b = k2_b; ma.v1_b = v1_b; ma.v2_b = v2_b;
    ma.g1_b = g1_b; ma.g2_b = g2_b;
    ma.K1f = K1f; ma.K2f = K2f; ma.V1b = V1b; ma.V2b = V2b;
    ma.Qb = Qb; ma.G1b = G1b; ma.G2b = G2b;
    mega_gemm<<<1408, 256, 0, stream>>>(ma);

    // 3) fused prep (K norms+cast, Q norms, V transpose)
    prep_kernel<<<26624, 256, 0, stream>>>(K1f, K2f, K1b, K2b, vv, aa, va,
                                           Qb, ll, V1b, V2b, V1t, V2t);

    // 4-7) attention + output projection
    scores_kernel<<<dim3(8, 4, 64), 256, 0, stream>>>(Qb, K1b, K2b, ll, vv, aa, va, logits);
    softmax_avg_kernel<<<2048, 256, 0, stream>>>(logits, out + (size_t)LQ * NB * EDIM);
    pv_gate_kernel<<<dim3(4, 64), 256, 0, stream>>>(attn, V1t, V2t, G1b, G2b, tmpb);
    gemm_o64<<<dim3(8, 32), 256, 0, stream>>>(tmpb, Wo, o_b, out);
}